// Round 12
// baseline (496.345 us; speedup 1.0000x reference)
//
#include <hip/hip_runtime.h>
#include <hip/hip_bf16.h>
#include <math.h>

#define HW 4096
#define NC 512
#define NB 4

typedef float f32x4 __attribute__((ext_vector_type(4)));
typedef float f32x16 __attribute__((ext_vector_type(16)));
typedef short bf16x8 __attribute__((ext_vector_type(8)));
typedef unsigned int u32;
typedef u32 u32x4 __attribute__((ext_vector_type(4)));
typedef unsigned short ushort_t;

#define GLOAD_LDS(g, s) __builtin_amdgcn_global_load_lds((const __attribute__((address_space(1))) void*)(g), (__attribute__((address_space(3))) void*)(s), 16, 0, 0)

__device__ __forceinline__ unsigned short f2bf(float f){
  unsigned int u = __builtin_bit_cast(unsigned int, f);
  u += 0x7FFFu + ((u >> 16) & 1u);
  return (unsigned short)(u >> 16);
}
__device__ __forceinline__ float bf2f(unsigned short h){
  unsigned int u = ((unsigned int)h) << 16;
  return __builtin_bit_cast(float, u);
}

// ---------------- W -> bf16 hi (+lo for q/k rows 0..127) ----------------
__global__ __launch_bounds__(256) void wsplit_kernel(
    const float* __restrict__ Wq, const float* __restrict__ Wk,
    const float* __restrict__ Wv, ushort_t* __restrict__ wh, ushort_t* __restrict__ wl)
{
  long e = ((long)blockIdx.x * 256 + threadIdx.x) * 8;
  int r = (int)(e >> 9), c = (int)(e & 511);
  const float* src = (r < 64)  ? Wq + (long)r * 512 + c
                   : (r < 128) ? Wk + (long)(r - 64) * 512 + c
                               : Wv + (long)(r - 128) * 512 + c;
  f32x4 v0 = *reinterpret_cast<const f32x4*>(src);
  f32x4 v1 = *reinterpret_cast<const f32x4*>(src + 4);
  ushort_t h[8], l[8];
  #pragma unroll
  for (int j = 0; j < 4; j++){ h[j] = f2bf(v0[j]); l[j] = f2bf(v0[j] - bf2f(h[j])); }
  #pragma unroll
  for (int j = 0; j < 4; j++){ h[4+j] = f2bf(v1[j]); l[4+j] = f2bf(v1[j] - bf2f(h[4+j])); }
  *reinterpret_cast<bf16x8*>(wh + e) = *reinterpret_cast<bf16x8*>(h);
  if (r < 128) *reinterpret_cast<bf16x8*>(wl + e) = *reinterpret_cast<bf16x8*>(l);
}

// ---------------- x [b][c][px] fp32 -> xt hi/lo [b][px][c] bf16 ----------------
__global__ __launch_bounds__(256) void split_kernel(
    const float* __restrict__ x, ushort_t* __restrict__ xth, ushort_t* __restrict__ xtl)
{
  const int i0 = blockIdx.x * 64;
  const int c0 = blockIdx.y * 64;
  const int b  = blockIdx.z;
  const int tid = threadIdx.x;
  const int tx = tid & 63, ty = tid >> 6;
  __shared__ float ts[64][65];
  #pragma unroll
  for (int u = 0; u < 16; u++){
    int cl = ty * 16 + u;
    ts[cl][tx] = x[((long)b * NC + c0 + cl) * HW + i0 + tx];
  }
  __syncthreads();
  const int px = tid >> 2;
  const int cs = (tid & 3) * 16;
  ushort_t h[16], l[16];
  #pragma unroll
  for (int e = 0; e < 16; e++){
    float v = ts[cs + e][px];
    h[e] = f2bf(v);
    l[e] = f2bf(v - bf2f(h[e]));
  }
  long base = ((long)b * HW + i0 + px) * 512 + c0 + cs;
  *reinterpret_cast<bf16x8*>(xth + base)     = *reinterpret_cast<bf16x8*>(h);
  *reinterpret_cast<bf16x8*>(xth + base + 8) = *reinterpret_cast<bf16x8*>(h + 8);
  *reinterpret_cast<bf16x8*>(xtl + base)     = *reinterpret_cast<bf16x8*>(l);
  *reinterpret_cast<bf16x8*>(xtl + base + 8) = *reinterpret_cast<bf16x8*>(l + 8);
}

// ---------------- MFMA projection GEMM (q pre-scaled by log2 e) ----------------
__global__ __launch_bounds__(256) void gemm_kernel(
    const ushort_t* __restrict__ xth, const ushort_t* __restrict__ xtl,
    const ushort_t* __restrict__ wh, const ushort_t* __restrict__ wl,
    const float* __restrict__ bq, const float* __restrict__ bk, const float* __restrict__ bv,
    ushort_t* __restrict__ qhi, ushort_t* __restrict__ qlo,
    ushort_t* __restrict__ khi, ushort_t* __restrict__ klo,
    ushort_t* __restrict__ vv)
{
  extern __shared__ char lds[];
  const int it = blockIdx.x;
  const int rg = blockIdx.y;
  const int b  = blockIdx.z;
  const int i0 = it * 128;
  const int tid = threadIdx.x;
  const int w = tid >> 6;
  const int lane = tid & 63;
  const int g = lane >> 4, n = lane & 15;
  const int wy = w >> 1, wx = w & 1;

  f32x4 acc[4][4];
  #pragma unroll
  for (int a = 0; a < 4; a++)
    #pragma unroll
    for (int m = 0; m < 4; m++) acc[a][m] = (f32x4){0.f, 0.f, 0.f, 0.f};

  const long xrow = (long)b * HW + i0;

  auto stage = [&](int bsel, int c0s){
    char* dbase = lds + bsel * 32768 + (w << 10);
    #pragma unroll
    for (int u = 0; u < 4; u++){
      int idx = (u << 8) | tid;
      int px = idx >> 3;
      int chs = (idx & 7) ^ (px & 7);
      long go = (xrow + px) * 512 + c0s + chs * 8;
      GLOAD_LDS(xth + go, dbase + (u << 12));
      GLOAD_LDS(xtl + go, dbase + 16384 + (u << 12));
    }
  };

  stage(0, 0);
  asm volatile("s_waitcnt vmcnt(0)" ::: "memory");
  __syncthreads();

  int cur = 0;
  for (int t = 0; t < 8; t++){
    const int c0 = t << 6;
    bf16x8 wfh[4][2], wfl[4][2];
    #pragma unroll
    for (int a = 0; a < 4; a++){
      long R = (long)(rg * 128 + wx * 64 + a * 16 + n) * 512 + c0 + g * 8;
      wfh[a][0] = *reinterpret_cast<const bf16x8*>(wh + R);
      wfh[a][1] = *reinterpret_cast<const bf16x8*>(wh + R + 32);
    }
    if (rg == 0){
      #pragma unroll
      for (int a = 0; a < 4; a++){
        long R = (long)(wx * 64 + a * 16 + n) * 512 + c0 + g * 8;
        wfl[a][0] = *reinterpret_cast<const bf16x8*>(wl + R);
        wfl[a][1] = *reinterpret_cast<const bf16x8*>(wl + R + 32);
      }
    }
    if (t < 7) stage(cur ^ 1, (t + 1) << 6);
    bf16x8 xh[4][2], xl[4][2];
    const char* buf = lds + cur * 32768;
    #pragma unroll
    for (int m = 0; m < 4; m++){
      int px = wy * 64 + m * 16 + n;
      const char* row = buf + px * 128;
      #pragma unroll
      for (int ks = 0; ks < 2; ks++){
        int off = (((ks << 2) | g) ^ (px & 7)) << 4;
        xh[m][ks] = *reinterpret_cast<const bf16x8*>(row + off);
        xl[m][ks] = *reinterpret_cast<const bf16x8*>(row + 16384 + off);
      }
    }
    __builtin_amdgcn_s_setprio(1);
    if (rg == 0){
      #pragma unroll
      for (int a = 0; a < 4; a++)
        #pragma unroll
        for (int m = 0; m < 4; m++)
          #pragma unroll
          for (int ks = 0; ks < 2; ks++){
            acc[a][m] = __builtin_amdgcn_mfma_f32_16x16x32_bf16(xh[m][ks], wfh[a][ks], acc[a][m], 0, 0, 0);
            acc[a][m] = __builtin_amdgcn_mfma_f32_16x16x32_bf16(xl[m][ks], wfh[a][ks], acc[a][m], 0, 0, 0);
            acc[a][m] = __builtin_amdgcn_mfma_f32_16x16x32_bf16(xh[m][ks], wfl[a][ks], acc[a][m], 0, 0, 0);
          }
    } else {
      #pragma unroll
      for (int a = 0; a < 4; a++)
        #pragma unroll
        for (int m = 0; m < 4; m++)
          #pragma unroll
          for (int ks = 0; ks < 2; ks++){
            acc[a][m] = __builtin_amdgcn_mfma_f32_16x16x32_bf16(wfh[a][ks], xh[m][ks], acc[a][m], 0, 0, 0);
            acc[a][m] = __builtin_amdgcn_mfma_f32_16x16x32_bf16(wfh[a][ks], xl[m][ks], acc[a][m], 0, 0, 0);
          }
    }
    __builtin_amdgcn_s_setprio(0);
    asm volatile("s_waitcnt vmcnt(0)" ::: "memory");
    __syncthreads();
    cur ^= 1;
  }

  if (rg == 0){
    ushort_t* hs = wx ? khi : qhi;
    ushort_t* ls = wx ? klo : qlo;
    const float* bias = wx ? bk : bq;
    const float qscale = wx ? 1.0f : 1.44269504088896f;
    #pragma unroll
    for (int a = 0; a < 4; a++){
      float bb = bias[a * 16 + n];
      #pragma unroll
      for (int m = 0; m < 4; m++){
        #pragma unroll
        for (int r4 = 0; r4 < 4; r4++){
          int px = wy * 64 + m * 16 + g * 4 + r4;
          float v = (acc[a][m][r4] + bb) * qscale;
          ushort_t h = f2bf(v);
          ushort_t l = f2bf(v - bf2f(h));
          long ad = (xrow + px) * 64 + a * 16 + n;
          hs[ad] = h;
          ls[ad] = l;
        }
      }
    }
  } else {
    #pragma unroll
    for (int a = 0; a < 4; a++){
      #pragma unroll
      for (int r4 = 0; r4 < 4; r4++){
        int C = (rg - 1) * 128 + wx * 64 + a * 16 + g * 4 + r4;
        float bb = bv[C];
        #pragma unroll
        for (int m = 0; m < 4; m++){
          int px = wy * 64 + m * 16 + n;
          vv[((long)b * NC + C) * HW + i0 + px] = f2bf(acc[a][m][r4] + bb);
        }
      }
    }
  }
}

// ---------------- flash attention: split softmax across ch-pair, lazy common max ----------------
// 1D grid 256; decode: xcd = wgid&7 -> (jh, b), qt = wgid>>3.
// 8 waves: rg = w>>1 (32 q rows), ch = w&1 (256-c half AND 32-j half of QK).
// 32 iters x 64-j tiles. Per iter:
//   step1: lazy-max update (own+partner tmx from t-1, parity dbuf); QK on own 32-j
//          half (8 MFMA); tmx publish; P=exp2(S-m); pack -> own pa[2]; publish.
//   bar1.  step2: read partner pa[2]; stage K[t+1] (single buf, K[t] dead) and
//          V[t+1] (dbuf); PV 32 MFMA; bar2.
// m(t) built only from tile maxima up to t-1 (common to both waves) -> both
// halves share normalization; P bounded by 2^(lag); f32/bf16 exponent-safe.
// LDS 154K: [0,8K) K | [8K,136K) V dbuf | [136K,152K) pa (2K/wave, 2 planes)
//           | [152K,+2K) tmx parity dbuf
__global__ __launch_bounds__(512, 1) void attn_kernel(
    const ushort_t* __restrict__ qhi, const ushort_t* __restrict__ qlo,
    const ushort_t* __restrict__ khi,
    const ushort_t* __restrict__ vv,
    ushort_t* __restrict__ p0, ushort_t* __restrict__ p1,
    float* __restrict__ mbuf, float* __restrict__ lbuf)
{
  extern __shared__ char smem[];
  const int VB = 8192, PA = 139264, TM = 155648;
  const int wgid = blockIdx.x;
  const int xcd = wgid & 7;
  const int jh = xcd >> 2;
  const int b  = xcd & 3;
  const int qt = wgid >> 3;
  const int tid = threadIdx.x;
  const int w = tid >> 6;
  const int lane = tid & 63;
  const int q32 = lane & 31;
  const int hh = lane >> 5;
  const int rg = w >> 1, ch = w & 1;
  const int i0w = qt * 128 + rg * 32;
  const int c0w = ch * 256;
  const int jbase = jh * 2048;

  // Q fragments (B-operand): col q = lane&31, k(d) = c*16 + hh*8 + e
  bf16x8 aqh[4], aql[4];
  #pragma unroll
  for (int c = 0; c < 4; c++){
    long qb = ((long)b * HW + i0w + q32) * 64 + c * 16 + hh * 8;
    aqh[c] = *reinterpret_cast<const bf16x8*>(qhi + qb);
    aql[c] = *reinterpret_cast<const bf16x8*>(qlo + qb);
  }

  f32x16 acc[8];
  #pragma unroll
  for (int ct = 0; ct < 8; ct++)
    #pragma unroll
    for (int r = 0; r < 16; r++) acc[ct][r] = 0.f;
  float mrow = 0.f, lrow = 0.f, tmx_prev = -1e30f;

  auto stageK = [&](int j0){
    int ci = (w << 6) | lane;
    int kj = ci >> 3, pos = ci & 7;
    int db = pos ^ (kj & 7);
    GLOAD_LDS(khi + ((long)b * HW + j0 + kj) * 64 + db * 8, smem + (w << 10));
  };
  auto stageV = [&](int vbsel, int j0){
    char* dbase = smem + VB + (vbsel << 16) + (w << 10);
    #pragma unroll
    for (int r = 0; r < 8; r++){
      int ss = (r << 9) | tid;
      int c = ss >> 3;
      int jblk = (ss & 7) ^ (c & 7);
      GLOAD_LDS(vv + ((long)b * NC + c) * HW + j0 + jblk * 8, dbase + (r << 13));
    }
  };

  // prologue: K[0], V[0]
  stageK(jbase);
  stageV(0, jbase);
  asm volatile("s_waitcnt vmcnt(0)" ::: "memory");
  __syncthreads();

  int cur = 0;
  for (int t = 0; t < 32; t++){
    // ---- step 1: lazy common-max update from t-1 tile maxima
    if (t > 0){
      float ptmx = *(const float*)(smem + TM + (((t - 1) & 1) << 10) + ((w ^ 1) << 7) + (q32 << 2));
      float cand = fmaxf(tmx_prev, ptmx);
      if (__any(cand > mrow + 11.5f)){
        float mnew = fmaxf(mrow, cand);
        float sc = exp2f(mrow - mnew);
        lrow *= sc;
        #pragma unroll
        for (int ct = 0; ct < 8; ct++)
          #pragma unroll
          for (int r = 0; r < 16; r++) acc[ct][r] *= sc;
        mrow = mnew;
      }
    }
    // QK on own 32-j half (jt = ch): S[j, q], 2-term, log2 domain
    f32x16 sv;
    {
      int jrow = ch * 32 + q32;
      const char* krow = smem + jrow * 128;
      int r7 = jrow & 7;
      f32x16 s1, s2;
      #pragma unroll
      for (int r = 0; r < 16; r++){ s1[r] = 0.f; s2[r] = 0.f; }
      __builtin_amdgcn_s_setprio(1);
      #pragma unroll
      for (int c = 0; c < 4; c++){
        int off = (((c << 1) | hh) ^ r7) << 4;
        bf16x8 kh = *(const bf16x8*)(krow + off);
        s1 = __builtin_amdgcn_mfma_f32_32x32x16_bf16(kh, aqh[c], s1, 0, 0, 0);
        s2 = __builtin_amdgcn_mfma_f32_32x32x16_bf16(kh, aql[c], s2, 0, 0, 0);
      }
      __builtin_amdgcn_s_setprio(0);
      #pragma unroll
      for (int r = 0; r < 16; r++) sv[r] = s1[r] + s2[r];
    }
    // own tile max over own half (16 regs + hh partner via shfl), publish (parity)
    {
      float m8[8];
      #pragma unroll
      for (int r = 0; r < 8; r++) m8[r] = fmaxf(sv[r], sv[r + 8]);
      float m4a = fmaxf(m8[0], m8[4]), m4b = fmaxf(m8[1], m8[5]);
      float m4c = fmaxf(m8[2], m8[6]), m4d = fmaxf(m8[3], m8[7]);
      float tmx = fmaxf(fmaxf(m4a, m4b), fmaxf(m4c, m4d));
      tmx = fmaxf(tmx, __shfl_xor(tmx, 32));
      if (hh == 0)
        *(float*)(smem + TM + ((t & 1) << 10) + (w << 7) + (q32 << 2)) = tmx;
      tmx_prev = tmx;
    }
    // P = exp2(S - m) (may exceed 1 under lag; exponent-safe), sum, pack own pa[2]
    bf16x8 own0, own1;
    {
      #pragma unroll
      for (int r = 0; r < 16; r++) sv[r] = exp2f(sv[r] - mrow);
      float rs = 0.f;
      #pragma unroll
      for (int r = 0; r < 16; r++) rs += sv[r];
      rs += __shfl_xor(rs, 32);
      lrow += rs;
      u32 pk[8];
      #pragma unroll
      for (int i = 0; i < 8; i++){
        float a = sv[2 * i], bb = sv[2 * i + 1];
        u32 d;
        asm("v_cvt_pk_bf16_f32 %0, %1, %2" : "=v"(d) : "v"(a), "v"(bb));
        pk[i] = d;
      }
      u32 a0 = pk[0], b0 = pk[2], a1 = pk[1], b1 = pk[3];
      asm volatile("v_permlane32_swap_b32 %0, %1" : "+v"(a0), "+v"(b0));
      asm volatile("v_permlane32_swap_b32 %0, %1" : "+v"(a1), "+v"(b1));
      u32x4 wv0; wv0[0] = a0; wv0[1] = a1; wv0[2] = b0; wv0[3] = b1;
      own0 = __builtin_bit_cast(bf16x8, wv0);
      u32 a2 = pk[4], b2 = pk[6], a3 = pk[5], b3 = pk[7];
      asm volatile("v_permlane32_swap_b32 %0, %1" : "+v"(a2), "+v"(b2));
      asm volatile("v_permlane32_swap_b32 %0, %1" : "+v"(a3), "+v"(b3));
      u32x4 wv1; wv1[0] = a2; wv1[1] = a3; wv1[2] = b2; wv1[3] = b3;
      own1 = __builtin_bit_cast(bf16x8, wv1);
      char* pb = smem + PA + (w << 11);
      *reinterpret_cast<bf16x8*>(pb + (lane << 4)) = own0;
      *reinterpret_cast<bf16x8*>(pb + 1024 + (lane << 4)) = own1;
    }
    __syncthreads();   // bar1: pa + tmx published
    // ---- step 2: assemble pa[4], stage next tile, PV
    bf16x8 pa4[4];
    {
      pa4[ch * 2 + 0] = own0;
      pa4[ch * 2 + 1] = own1;
      const char* qb2 = smem + PA + ((w ^ 1) << 11);
      pa4[(1 - ch) * 2 + 0] = *reinterpret_cast<const bf16x8*>(qb2 + (lane << 4));
      pa4[(1 - ch) * 2 + 1] = *reinterpret_cast<const bf16x8*>(qb2 + 1024 + (lane << 4));
    }
    if (t < 31){
      stageK(jbase + (t + 1) * 64);
      stageV(cur ^ 1, jbase + (t + 1) * 64);
    }
    {
      const char* vb = smem + VB + (cur << 16);
      __builtin_amdgcn_s_setprio(1);
      #pragma unroll
      for (int ct = 0; ct < 8; ct++){
        int row = c0w + ct * 32 + q32;
        const char* vrow = vb + row * 128;
        int r7 = row & 7;
        #pragma unroll
        for (int c = 0; c < 4; c++){
          int off = (((c << 1) | hh) ^ r7) << 4;
          bf16x8 vf = *(const bf16x8*)(vrow + off);
          acc[ct] = __builtin_amdgcn_mfma_f32_32x32x16_bf16(vf, pa4[c], acc[ct], 0, 0, 0);
        }
      }
      __builtin_amdgcn_s_setprio(0);
    }
    __syncthreads();   // bar2: K[t+1]/V[t+1] landed (implicit drain), buffers publish
    cur ^= 1;
  }

  // epilogue: unnormalized partial bf16, [b][c][i] layout (coalesced in i)
  ushort_t* pd = jh ? p1 : p0;
  const int i = i0w + q32;
  #pragma unroll
  for (int ct = 0; ct < 8; ct++){
    #pragma unroll
    for (int r = 0; r < 16; r++){
      int c = c0w + ct * 32 + (r & 3) + 8 * (r >> 2) + 4 * hh;
      pd[((long)b * NC + c) * HW + i] = f2bf(acc[ct][r]);
    }
  }
  if (lane < 32){
    int gi = b * HW + i0w + lane;
    if (ch == 0) mbuf[jh * (NB * HW) + gi] = mrow;
    lbuf[(jh * 2 + ch) * (NB * HW) + gi] = lrow;
  }
}

// ---------------- combine halves + epilogue: out = gamma * O + x ----------------
__global__ __launch_bounds__(256) void comb_kernel(
    const ushort_t* __restrict__ p0, const ushort_t* __restrict__ p1,
    const float* __restrict__ mbuf, const float* __restrict__ lbuf,
    const float* __restrict__ x, const float* __restrict__ gamma,
    float* __restrict__ out)
{
  const int NBHW = NB * HW;
  const int it = blockIdx.x;
  const int ct = blockIdx.y;
  const int b  = blockIdx.z;
  const int i0 = it * 64, c0 = ct * 64;
  const int tid = threadIdx.x;
  const int tx = tid & 63, ty = tid >> 6;
  __shared__ float f0s[64], f1s[64];
  const float gm = gamma[0];
  if (tid < 64){
    int gi = b * HW + i0 + tid;
    float m0 = mbuf[gi], m1 = mbuf[NBHW + gi];
    float l0 = lbuf[gi] + lbuf[NBHW + gi];            // jh=0: ch0+ch1
    float l1 = lbuf[2 * NBHW + gi] + lbuf[3 * NBHW + gi];  // jh=1
    float M = fmaxf(m0, m1);
    float w0 = exp2f(m0 - M), w1 = exp2f(m1 - M);
    float rden = 1.f / (w0 * l0 + w1 * l1);
    f0s[tid] = w0 * rden;
    f1s[tid] = w1 * rden;
  }
  __syncthreads();
  #pragma unroll
  for (int u = 0; u < 16; u++){
    int cl = ty * 16 + u;
    long idx = ((long)b * NC + c0 + cl) * HW + i0 + tx;
    float o = f0s[tx] * bf2f(p0[idx]) + f1s[tx] * bf2f(p1[idx]);
    out[idx] = fmaf(gm, o, x[idx]);
  }
}

extern "C" void kernel_launch(void* const* d_in, const int* in_sizes, int n_in,
                              void* d_out, int out_size, void* d_ws, size_t ws_size,
                              hipStream_t stream)
{
  const float* x  = (const float*)d_in[0];
  const float* Wq = (const float*)d_in[1];
  const float* bq = (const float*)d_in[2];
  const float* Wk = (const float*)d_in[3];
  const float* bk = (const float*)d_in[4];
  const float* Wv = (const float*)d_in[5];
  const float* bv = (const float*)d_in[6];
  const float* gamma = (const float*)d_in[7];
  float* out = (float*)d_out;

  char* ws = (char*)d_ws;
  const size_t MB = 1024 * 1024;
  ushort_t* xth = (ushort_t*)(ws);                 // 16 MB, reused as partial0
  ushort_t* xtl = (ushort_t*)(ws + 16 * MB);       // 16 MB, reused as partial1
  ushort_t* wh  = (ushort_t*)(ws + 32 * MB);       // 640 KB
  ushort_t* wl  = (ushort_t*)(ws + 32 * MB + 655360);  // 128 KB
  ushort_t* qhi = (ushort_t*)(ws + 33 * MB);       // 2 MB each
  ushort_t* qlo = (ushort_t*)(ws + 35 * MB);
  ushort_t* khi = (ushort_t*)(ws + 37 * MB);
  ushort_t* klo = (ushort_t*)(ws + 39 * MB);       // written by gemm, unused by attn
  ushort_t* vv  = (ushort_t*)(ws + 41 * MB);       // 16 MB
  float*    mbuf = (float*)(ws + 57 * MB);         // 2 x 64 KB
  float*    lbuf = (float*)(ws + 57 * MB + 131072);// 4 x 64 KB
  ushort_t* part0 = xth;
  ushort_t* part1 = xtl;

  wsplit_kernel<<<dim3(160), dim3(256), 0, stream>>>(Wq, Wk, Wv, wh, wl);
  split_kernel<<<dim3(64, 8, NB), dim3(256), 0, stream>>>(x, xth, xtl);

  const int GSMEM = 65536;
  hipFuncSetAttribute((const void*)gemm_kernel,
                      hipFuncAttributeMaxDynamicSharedMemorySize, GSMEM);
  gemm_kernel<<<dim3(32, 5, NB), dim3(256), GSMEM, stream>>>(
      xth, xtl, wh, wl, bq, bk, bv, qhi, qlo, khi, klo, vv);

  const int ASMEM = 157696;  // 8K K + 128K V dbuf + 16K pa + 2K tmx
  hipFuncSetAttribute((const void*)attn_kernel,
                      hipFuncAttributeMaxDynamicSharedMemorySize, ASMEM);
  attn_kernel<<<dim3(256), dim3(512), ASMEM, stream>>>(
      qhi, qlo, khi, vv, part0, part1, mbuf, lbuf);

  comb_kernel<<<dim3(64, 8, NB), dim3(256), 0, stream>>>(
      part0, part1, mbuf, lbuf, x, gamma, out);
}

// Round 13
// 201.912 us; speedup vs baseline: 2.4582x; 2.4582x over previous
//
#include <hip/hip_runtime.h>
#include <hip/hip_bf16.h>
#include <math.h>

#define HW 4096
#define NC 512
#define NB 4

typedef float f32x4 __attribute__((ext_vector_type(4)));
typedef float f32x16 __attribute__((ext_vector_type(16)));
typedef short bf16x8 __attribute__((ext_vector_type(8)));
typedef unsigned int u32;
typedef u32 u32x4 __attribute__((ext_vector_type(4)));
typedef unsigned short ushort_t;

#define GLOAD_LDS(g, s) __builtin_amdgcn_global_load_lds((const __attribute__((address_space(1))) void*)(g), (__attribute__((address_space(3))) void*)(s), 16, 0, 0)

__device__ __forceinline__ unsigned short f2bf(float f){
  unsigned int u = __builtin_bit_cast(unsigned int, f);
  u += 0x7FFFu + ((u >> 16) & 1u);
  return (unsigned short)(u >> 16);
}
__device__ __forceinline__ float bf2f(unsigned short h){
  unsigned int u = ((unsigned int)h) << 16;
  return __builtin_bit_cast(float, u);
}

// ---------------- W -> bf16 hi (+lo for q/k rows 0..127) ----------------
__global__ __launch_bounds__(256) void wsplit_kernel(
    const float* __restrict__ Wq, const float* __restrict__ Wk,
    const float* __restrict__ Wv, ushort_t* __restrict__ wh, ushort_t* __restrict__ wl)
{
  long e = ((long)blockIdx.x * 256 + threadIdx.x) * 8;
  int r = (int)(e >> 9), c = (int)(e & 511);
  const float* src = (r < 64)  ? Wq + (long)r * 512 + c
                   : (r < 128) ? Wk + (long)(r - 64) * 512 + c
                               : Wv + (long)(r - 128) * 512 + c;
  f32x4 v0 = *reinterpret_cast<const f32x4*>(src);
  f32x4 v1 = *reinterpret_cast<const f32x4*>(src + 4);
  ushort_t h[8], l[8];
  #pragma unroll
  for (int j = 0; j < 4; j++){ h[j] = f2bf(v0[j]); l[j] = f2bf(v0[j] - bf2f(h[j])); }
  #pragma unroll
  for (int j = 0; j < 4; j++){ h[4+j] = f2bf(v1[j]); l[4+j] = f2bf(v1[j] - bf2f(h[4+j])); }
  *reinterpret_cast<bf16x8*>(wh + e) = *reinterpret_cast<bf16x8*>(h);
  if (r < 128) *reinterpret_cast<bf16x8*>(wl + e) = *reinterpret_cast<bf16x8*>(l);
}

// ---------------- x [b][c][px] fp32 -> xt hi/lo [b][px][c] bf16 ----------------
__global__ __launch_bounds__(256) void split_kernel(
    const float* __restrict__ x, ushort_t* __restrict__ xth, ushort_t* __restrict__ xtl)
{
  const int i0 = blockIdx.x * 64;
  const int c0 = blockIdx.y * 64;
  const int b  = blockIdx.z;
  const int tid = threadIdx.x;
  const int tx = tid & 63, ty = tid >> 6;
  __shared__ float ts[64][65];
  #pragma unroll
  for (int u = 0; u < 16; u++){
    int cl = ty * 16 + u;
    ts[cl][tx] = x[((long)b * NC + c0 + cl) * HW + i0 + tx];
  }
  __syncthreads();
  const int px = tid >> 2;
  const int cs = (tid & 3) * 16;
  ushort_t h[16], l[16];
  #pragma unroll
  for (int e = 0; e < 16; e++){
    float v = ts[cs + e][px];
    h[e] = f2bf(v);
    l[e] = f2bf(v - bf2f(h[e]));
  }
  long base = ((long)b * HW + i0 + px) * 512 + c0 + cs;
  *reinterpret_cast<bf16x8*>(xth + base)     = *reinterpret_cast<bf16x8*>(h);
  *reinterpret_cast<bf16x8*>(xth + base + 8) = *reinterpret_cast<bf16x8*>(h + 8);
  *reinterpret_cast<bf16x8*>(xtl + base)     = *reinterpret_cast<bf16x8*>(l);
  *reinterpret_cast<bf16x8*>(xtl + base + 8) = *reinterpret_cast<bf16x8*>(l + 8);
}

// ---------------- MFMA projection GEMM (q pre-scaled by log2 e) ----------------
__global__ __launch_bounds__(256) void gemm_kernel(
    const ushort_t* __restrict__ xth, const ushort_t* __restrict__ xtl,
    const ushort_t* __restrict__ wh, const ushort_t* __restrict__ wl,
    const float* __restrict__ bq, const float* __restrict__ bk, const float* __restrict__ bv,
    ushort_t* __restrict__ qhi, ushort_t* __restrict__ qlo,
    ushort_t* __restrict__ khi, ushort_t* __restrict__ klo,
    ushort_t* __restrict__ vv)
{
  extern __shared__ char lds[];
  const int it = blockIdx.x;
  const int rg = blockIdx.y;
  const int b  = blockIdx.z;
  const int i0 = it * 128;
  const int tid = threadIdx.x;
  const int w = tid >> 6;
  const int lane = tid & 63;
  const int g = lane >> 4, n = lane & 15;
  const int wy = w >> 1, wx = w & 1;

  f32x4 acc[4][4];
  #pragma unroll
  for (int a = 0; a < 4; a++)
    #pragma unroll
    for (int m = 0; m < 4; m++) acc[a][m] = (f32x4){0.f, 0.f, 0.f, 0.f};

  const long xrow = (long)b * HW + i0;

  auto stage = [&](int bsel, int c0s){
    char* dbase = lds + bsel * 32768 + (w << 10);
    #pragma unroll
    for (int u = 0; u < 4; u++){
      int idx = (u << 8) | tid;
      int px = idx >> 3;
      int chs = (idx & 7) ^ (px & 7);
      long go = (xrow + px) * 512 + c0s + chs * 8;
      GLOAD_LDS(xth + go, dbase + (u << 12));
      GLOAD_LDS(xtl + go, dbase + 16384 + (u << 12));
    }
  };

  stage(0, 0);
  asm volatile("s_waitcnt vmcnt(0)" ::: "memory");
  __syncthreads();

  int cur = 0;
  for (int t = 0; t < 8; t++){
    const int c0 = t << 6;
    bf16x8 wfh[4][2], wfl[4][2];
    #pragma unroll
    for (int a = 0; a < 4; a++){
      long R = (long)(rg * 128 + wx * 64 + a * 16 + n) * 512 + c0 + g * 8;
      wfh[a][0] = *reinterpret_cast<const bf16x8*>(wh + R);
      wfh[a][1] = *reinterpret_cast<const bf16x8*>(wh + R + 32);
    }
    if (rg == 0){
      #pragma unroll
      for (int a = 0; a < 4; a++){
        long R = (long)(wx * 64 + a * 16 + n) * 512 + c0 + g * 8;
        wfl[a][0] = *reinterpret_cast<const bf16x8*>(wl + R);
        wfl[a][1] = *reinterpret_cast<const bf16x8*>(wl + R + 32);
      }
    }
    if (t < 7) stage(cur ^ 1, (t + 1) << 6);
    bf16x8 xh[4][2], xl[4][2];
    const char* buf = lds + cur * 32768;
    #pragma unroll
    for (int m = 0; m < 4; m++){
      int px = wy * 64 + m * 16 + n;
      const char* row = buf + px * 128;
      #pragma unroll
      for (int ks = 0; ks < 2; ks++){
        int off = (((ks << 2) | g) ^ (px & 7)) << 4;
        xh[m][ks] = *reinterpret_cast<const bf16x8*>(row + off);
        xl[m][ks] = *reinterpret_cast<const bf16x8*>(row + 16384 + off);
      }
    }
    __builtin_amdgcn_s_setprio(1);
    if (rg == 0){
      #pragma unroll
      for (int a = 0; a < 4; a++)
        #pragma unroll
        for (int m = 0; m < 4; m++)
          #pragma unroll
          for (int ks = 0; ks < 2; ks++){
            acc[a][m] = __builtin_amdgcn_mfma_f32_16x16x32_bf16(xh[m][ks], wfh[a][ks], acc[a][m], 0, 0, 0);
            acc[a][m] = __builtin_amdgcn_mfma_f32_16x16x32_bf16(xl[m][ks], wfh[a][ks], acc[a][m], 0, 0, 0);
            acc[a][m] = __builtin_amdgcn_mfma_f32_16x16x32_bf16(xh[m][ks], wfl[a][ks], acc[a][m], 0, 0, 0);
          }
    } else {
      #pragma unroll
      for (int a = 0; a < 4; a++)
        #pragma unroll
        for (int m = 0; m < 4; m++)
          #pragma unroll
          for (int ks = 0; ks < 2; ks++){
            acc[a][m] = __builtin_amdgcn_mfma_f32_16x16x32_bf16(wfh[a][ks], xh[m][ks], acc[a][m], 0, 0, 0);
            acc[a][m] = __builtin_amdgcn_mfma_f32_16x16x32_bf16(wfh[a][ks], xl[m][ks], acc[a][m], 0, 0, 0);
          }
    }
    __builtin_amdgcn_s_setprio(0);
    asm volatile("s_waitcnt vmcnt(0)" ::: "memory");
    __syncthreads();
    cur ^= 1;
  }

  if (rg == 0){
    ushort_t* hs = wx ? khi : qhi;
    ushort_t* ls = wx ? klo : qlo;
    const float* bias = wx ? bk : bq;
    const float qscale = wx ? 1.0f : 1.44269504088896f;  // q in log2 domain
    #pragma unroll
    for (int a = 0; a < 4; a++){
      float bb = bias[a * 16 + n];
      #pragma unroll
      for (int m = 0; m < 4; m++){
        #pragma unroll
        for (int r4 = 0; r4 < 4; r4++){
          int px = wy * 64 + m * 16 + g * 4 + r4;
          float v = (acc[a][m][r4] + bb) * qscale;
          ushort_t h = f2bf(v);
          ushort_t l = f2bf(v - bf2f(h));
          long ad = (xrow + px) * 64 + a * 16 + n;
          hs[ad] = h;
          ls[ad] = l;
        }
      }
    }
  } else {
    #pragma unroll
    for (int a = 0; a < 4; a++){
      #pragma unroll
      for (int r4 = 0; r4 < 4; r4++){
        int C = (rg - 1) * 128 + wx * 64 + a * 16 + g * 4 + r4;
        float bb = bv[C];
        #pragma unroll
        for (int m = 0; m < 4; m++){
          int px = wy * 64 + m * 16 + n;
          vv[((long)b * NC + C) * HW + i0 + px] = f2bf(acc[a][m][r4] + bb);
        }
      }
    }
  }
}

// ---------------- flash attention: producer/consumer softmax dedup (round-10 proven) ----------------
// 1D grid 256; decode: xcd = wgid&7 -> (jh = xcd>>2, b = xcd&3), qt = wgid>>3.
// Block 512 thr (8 waves): w<4 -> PRODUCER (rg=w, ch=0): QK + softmax + pack,
// publish pa/flag/sc via LDS. w>=4 -> CONSUMER (rg=w-4, ch=1): stage V[t+1] in
// phase 1, then stage K[t+1] + read pa + join PV in phase 2.
// LDS 153K: [0,8K) K single | [8K,136K) V dbuf | [136K,152K) P (4K/rg) | [152K,+1K) flags/sc
__global__ __launch_bounds__(512, 1) void attn_kernel(
    const ushort_t* __restrict__ qhi, const ushort_t* __restrict__ qlo,
    const ushort_t* __restrict__ khi,
    const ushort_t* __restrict__ vv,
    ushort_t* __restrict__ p0, ushort_t* __restrict__ p1,
    float* __restrict__ mbuf, float* __restrict__ lbuf)
{
  extern __shared__ char smem[];
  const int VB = 8192, PB = 139264, FB = 155648;
  const int wgid = blockIdx.x;
  const int xcd = wgid & 7;
  const int jh = xcd >> 2;
  const int b  = xcd & 3;
  const int qt = wgid >> 3;
  const int tid = threadIdx.x;
  const int w = tid >> 6;
  const int lane = tid & 63;
  const int q32 = lane & 31;
  const int hh = lane >> 5;
  const bool producer = (w < 4);
  const int rg = producer ? w : (w - 4);
  const int ch = producer ? 0 : 1;
  const int i0w = qt * 128 + rg * 32;
  const int c0w = ch * 256;
  const int jbase = jh * 2048;
  const int ct256 = ((w & 3) << 6) | lane;   // consumer staging index

  // Q fragments (B-operand): col q = lane&31, k(d) = c*16 + hh*8 + e
  bf16x8 aqh[4], aql[4];
  #pragma unroll
  for (int c = 0; c < 4; c++){
    long qb = ((long)b * HW + i0w + q32) * 64 + c * 16 + hh * 8;
    aqh[c] = *reinterpret_cast<const bf16x8*>(qhi + qb);
    aql[c] = *reinterpret_cast<const bf16x8*>(qlo + qb);
  }

  f32x16 acc[8];
  #pragma unroll
  for (int ct = 0; ct < 8; ct++)
    #pragma unroll
    for (int r = 0; r < 16; r++) acc[ct][r] = 0.f;
  float mrow = -1e30f, lrow = 0.f;

  // ---- prologue: all 512 threads stage K[0] (single buf) + V[0] (buf0)
  {
    int kj = tid >> 3;
    int kd = (tid & 7) ^ (kj & 7);
    GLOAD_LDS(khi + ((long)b * HW + jbase + kj) * 64 + kd * 8, smem + (w << 10));
    #pragma unroll
    for (int r = 0; r < 8; r++){
      int ss = (r << 9) | tid;
      int c = ss >> 3;
      int jblk = (ss & 7) ^ (c & 7);
      GLOAD_LDS(vv + ((long)b * NC + c) * HW + jbase + jblk * 8,
                smem + VB + (r << 13) + (w << 10));
    }
  }
  asm volatile("s_waitcnt vmcnt(0)" ::: "memory");
  __syncthreads();

  int cur = 0;
  for (int t = 0; t < 32; t++){
    bf16x8 pa[4];
    // ================= phase 1 =================
    if (producer){
      // QK swapped: S[j, q] = kh·(qh + ql), log2 domain (K single buffer)
      f32x16 sv[2];
      __builtin_amdgcn_s_setprio(1);
      #pragma unroll
      for (int jt = 0; jt < 2; jt++){
        int jrow = jt * 32 + q32;
        const char* krow = smem + jrow * 128;
        int r7 = jrow & 7;
        f32x16 s;
        #pragma unroll
        for (int r = 0; r < 16; r++) s[r] = 0.f;
        #pragma unroll
        for (int c = 0; c < 4; c++){
          int off = (((c << 1) | hh) ^ r7) << 4;
          bf16x8 kh = *(const bf16x8*)(krow + off);
          s = __builtin_amdgcn_mfma_f32_32x32x16_bf16(kh, aqh[c], s, 0, 0, 0);
          s = __builtin_amdgcn_mfma_f32_32x32x16_bf16(kh, aql[c], s, 0, 0, 0);
        }
        sv[jt] = s;
      }
      __builtin_amdgcn_s_setprio(0);
      // softmax with defer-max (log2 units)
      f32x16 mx;
      #pragma unroll
      for (int r = 0; r < 16; r++) mx[r] = fmaxf(sv[0][r], sv[1][r]);
      float m8[8];
      #pragma unroll
      for (int r = 0; r < 8; r++) m8[r] = fmaxf(mx[r], mx[r + 8]);
      float m4a = fmaxf(m8[0], m8[4]), m4b = fmaxf(m8[1], m8[5]);
      float m4c = fmaxf(m8[2], m8[6]), m4d = fmaxf(m8[3], m8[7]);
      float tmx = fmaxf(fmaxf(m4a, m4b), fmaxf(m4c, m4d));
      tmx = fmaxf(tmx, __shfl_xor(tmx, 32));
      int upd = __any(tmx > mrow + 11.5f) ? 1 : 0;
      float sc = 1.f;
      if (upd){
        float mnew = fmaxf(mrow, tmx);
        sc = exp2f(mrow - mnew);
        lrow *= sc;
        #pragma unroll
        for (int ct = 0; ct < 8; ct++)
          #pragma unroll
          for (int r = 0; r < 16; r++) acc[ct][r] *= sc;
        mrow = mnew;
      }
      // P = exp2(S - m), row-sum, pack
      #pragma unroll
      for (int jt = 0; jt < 2; jt++)
        #pragma unroll
        for (int r = 0; r < 16; r++) sv[jt][r] = exp2f(sv[jt][r] - mrow);
      float rs = 0.f;
      #pragma unroll
      for (int r = 0; r < 16; r++) rs += sv[0][r] + sv[1][r];
      rs += __shfl_xor(rs, 32);
      lrow += rs;
      #pragma unroll
      for (int jt = 0; jt < 2; jt++){
        u32 pk[8];
        #pragma unroll
        for (int i = 0; i < 8; i++){
          float a = sv[jt][2 * i], bb = sv[jt][2 * i + 1];
          u32 d;
          asm("v_cvt_pk_bf16_f32 %0, %1, %2" : "=v"(d) : "v"(a), "v"(bb));
          pk[i] = d;
        }
        #pragma unroll
        for (int cc = 0; cc < 2; cc++){
          u32 a0 = pk[4 * cc + 0], b0 = pk[4 * cc + 2];
          u32 a1 = pk[4 * cc + 1], b1 = pk[4 * cc + 3];
          asm volatile("v_permlane32_swap_b32 %0, %1" : "+v"(a0), "+v"(b0));
          asm volatile("v_permlane32_swap_b32 %0, %1" : "+v"(a1), "+v"(b1));
          u32x4 wv;
          wv[0] = a0; wv[1] = a1; wv[2] = b0; wv[3] = b1;
          pa[jt * 2 + cc] = __builtin_bit_cast(bf16x8, wv);
        }
      }
      // publish pa (XOR'd 16B chunks), flag, sc
      char* pb = smem + PB + rg * 4096 + lane * 64;
      #pragma unroll
      for (int i = 0; i < 4; i++)
        *reinterpret_cast<bf16x8*>(pb + ((i ^ (lane & 3)) << 4)) = pa[i];
      if (lane == 0) *(int*)(smem + FB + rg * 4) = upd;
      if (upd && hh == 0) *(float*)(smem + FB + 64 + rg * 128 + q32 * 4) = sc;
    } else {
      // consumer: stage V[t+1] -> vbuf^1 (16 loads; lands by end-of-iter vmcnt)
      if (t < 31){
        char* dbase = smem + VB + ((cur ^ 1) << 16) + ((w & 3) << 10);
        int j0 = jbase + (t + 1) * 64;
        #pragma unroll
        for (int r = 0; r < 16; r++){
          int ss = (r << 8) | ct256;
          int c = ss >> 3;
          int jblk = (ss & 7) ^ (c & 7);
          GLOAD_LDS(vv + ((long)b * NC + c) * HW + j0 + jblk * 8, dbase + (r << 12));
        }
      }
    }
    __syncthreads();   // bar1: pa/flag/sc published; V[t] settled reads done
    // ================= phase 2 =================
    if (!producer){
      // stage K[t+1] into the single K buffer (readers done at bar1)
      if (t < 31){
        int j0 = jbase + (t + 1) * 64;
        #pragma unroll
        for (int r = 0; r < 2; r++){
          int chunk = (r << 8) | ct256;
          int kj = chunk >> 3;
          int kd = (chunk & 7) ^ (kj & 7);
          GLOAD_LDS(khi + ((long)b * HW + j0 + kj) * 64 + kd * 8,
                    smem + (r << 12) + ((w & 3) << 10));
        }
      }
      // fetch pa + rescale decision from producer
      const char* pb = smem + PB + rg * 4096 + lane * 64;
      #pragma unroll
      for (int i = 0; i < 4; i++)
        pa[i] = *reinterpret_cast<const bf16x8*>(pb + ((i ^ (lane & 3)) << 4));
      int updf = *(const int*)(smem + FB + rg * 4);
      if (updf){
        float sc = *(const float*)(smem + FB + 64 + rg * 128 + q32 * 4);
        #pragma unroll
        for (int ct = 0; ct < 8; ct++)
          #pragma unroll
          for (int r = 0; r < 16; r++) acc[ct][r] *= sc;
      }
    }
    // PV on V[cur] (both producer and consumer, disjoint c-halves)
    {
      const char* vb = smem + VB + (cur << 16);
      __builtin_amdgcn_s_setprio(1);
      #pragma unroll
      for (int ct = 0; ct < 8; ct++){
        int row = c0w + ct * 32 + q32;
        const char* vrow = vb + row * 128;
        int r7 = row & 7;
        #pragma unroll
        for (int c = 0; c < 4; c++){
          int off = (((c << 1) | hh) ^ r7) << 4;
          bf16x8 vf = *(const bf16x8*)(vrow + off);
          acc[ct] = __builtin_amdgcn_mfma_f32_32x32x16_bf16(vf, pa[c], acc[ct], 0, 0, 0);
        }
      }
      __builtin_amdgcn_s_setprio(0);
    }
    // bar2: drain own staging (V issued ph1, K issued ph2), publish buffers
    asm volatile("s_waitcnt vmcnt(0)" ::: "memory");
    __syncthreads();
    cur ^= 1;
  }

  // epilogue: unnormalized partial bf16, [b][c][i] layout (coalesced in i)
  ushort_t* pd = jh ? p1 : p0;
  const int i = i0w + q32;
  #pragma unroll
  for (int ct = 0; ct < 8; ct++){
    #pragma unroll
    for (int r = 0; r < 16; r++){
      int c = c0w + ct * 32 + (r & 3) + 8 * (r >> 2) + 4 * hh;
      pd[((long)b * NC + c) * HW + i] = f2bf(acc[ct][r]);
    }
  }
  if (producer && lane < 32){
    int gi = b * HW + i0w + lane;
    mbuf[jh * (NB * HW) + gi] = mrow;
    lbuf[jh * (NB * HW) + gi] = lrow;
  }
}

// ---------------- combine halves + epilogue: out = gamma * O + x (vectorized) ----------------
// grid (32 i-tiles of 128, 8 c-tiles of 64, NB), 256 thr; 8 i per thread per u.
__global__ __launch_bounds__(256) void comb_kernel(
    const ushort_t* __restrict__ p0, const ushort_t* __restrict__ p1,
    const float* __restrict__ mbuf, const float* __restrict__ lbuf,
    const float* __restrict__ x, const float* __restrict__ gamma,
    float* __restrict__ out)
{
  const int it = blockIdx.x;
  const int ct = blockIdx.y;
  const int b  = blockIdx.z;
  const int i0 = it * 128, c0 = ct * 64;
  const int tid = threadIdx.x;
  __shared__ float f0s[128], f1s[128];
  const float gm = gamma[0];
  if (tid < 128){
    int gi = b * HW + i0 + tid;
    float m0 = mbuf[gi], m1 = mbuf[NB * HW + gi];
    float l0 = lbuf[gi], l1 = lbuf[NB * HW + gi];
    float M = fmaxf(m0, m1);
    float w0 = exp2f(m0 - M), w1 = exp2f(m1 - M);  // m in log2 units
    float rden = 1.f / (w0 * l0 + w1 * l1);
    f0s[tid] = w0 * rden;
    f1s[tid] = w1 * rden;
  }
  __syncthreads();
  const int ig = (tid & 15) << 3;   // i-local, 8-aligned
  const int cb = tid >> 4;          // 0..15
  #pragma unroll
  for (int u = 0; u < 4; u++){
    int cl = c0 + cb + u * 16;
    long base = ((long)b * NC + cl) * HW + i0 + ig;
    bf16x8 a0 = *reinterpret_cast<const bf16x8*>(p0 + base);
    bf16x8 a1 = *reinterpret_cast<const bf16x8*>(p1 + base);
    f32x4 x0 = *reinterpret_cast<const f32x4*>(x + base);
    f32x4 x1 = *reinterpret_cast<const f32x4*>(x + base + 4);
    f32x4 o0, o1;
    #pragma unroll
    for (int e = 0; e < 4; e++){
      float v = f0s[ig + e] * bf2f((ushort_t)a0[e]) + f1s[ig + e] * bf2f((ushort_t)a1[e]);
      o0[e] = fmaf(gm, v, x0[e]);
    }
    #pragma unroll
    for (int e = 0; e < 4; e++){
      float v = f0s[ig + 4 + e] * bf2f((ushort_t)a0[4 + e]) + f1s[ig + 4 + e] * bf2f((ushort_t)a1[4 + e]);
      o1[e] = fmaf(gm, v, x1[e]);
    }
    *reinterpret_cast<f32x4*>(out + base) = o0;
    *reinterpret_cast<f32x4*>(out + base + 4) = o1;
  }
}

extern "C" void kernel_launch(void* const* d_in, const int* in_sizes, int n_in,
                              void* d_out, int out_size, void* d_ws, size_t ws_size,
                              hipStream_t stream)
{
  const float* x  = (const float*)d_in[0];
  const float* Wq = (const float*)d_in[1];
  const float* bq = (const float*)d_in[2];
  const float* Wk = (const float*)d_in[3];
  const float* bk = (const float*)d_in[4];
  const float* Wv = (const float*)d_in[5];
  const float* bv = (const float*)d_in[6];
  const float* gamma = (const float*)d_in[7];
  float* out = (float*)d_out;

  char* ws = (char*)d_ws;
  const size_t MB = 1024 * 1024;
  ushort_t* xth = (ushort_t*)(ws);                 // 16 MB, reused as partial0
  ushort_t* xtl = (ushort_t*)(ws + 16 * MB);       // 16 MB, reused as partial1
  ushort_t* wh  = (ushort_t*)(ws + 32 * MB);       // 640 KB
  ushort_t* wl  = (ushort_t*)(ws + 32 * MB + 655360);  // 128 KB
  ushort_t* qhi = (ushort_t*)(ws + 33 * MB);       // 2 MB each
  ushort_t* qlo = (ushort_t*)(ws + 35 * MB);
  ushort_t* khi = (ushort_t*)(ws + 37 * MB);
  ushort_t* klo = (ushort_t*)(ws + 39 * MB);       // written by gemm, unused by attn
  ushort_t* vv  = (ushort_t*)(ws + 41 * MB);       // 16 MB
  float*    mbuf = (float*)(ws + 57 * MB);         // 128 KB
  float*    lbuf = (float*)(ws + 57 * MB + 131072);// 128 KB
  ushort_t* part0 = xth;   // alias: xt dead after gemm
  ushort_t* part1 = xtl;

  wsplit_kernel<<<dim3(160), dim3(256), 0, stream>>>(Wq, Wk, Wv, wh, wl);
  split_kernel<<<dim3(64, 8, NB), dim3(256), 0, stream>>>(x, xth, xtl);

  const int GSMEM = 65536;
  hipFuncSetAttribute((const void*)gemm_kernel,
                      hipFuncAttributeMaxDynamicSharedMemorySize, GSMEM);
  gemm_kernel<<<dim3(32, 5, NB), dim3(256), GSMEM, stream>>>(
      xth, xtl, wh, wl, bq, bk, bv, qhi, qlo, khi, klo, vv);

  const int ASMEM = 156672;  // 8K K + 128K V dbuf + 16K P + 1K flags
  hipFuncSetAttribute((const void*)attn_kernel,
                      hipFuncAttributeMaxDynamicSharedMemorySize, ASMEM);
  attn_kernel<<<dim3(256), dim3(512), ASMEM, stream>>>(
      qhi, qlo, khi, vv, part0, part1, mbuf, lbuf);

  comb_kernel<<<dim3(32, 8, NB), dim3(256), 0, stream>>>(
      part0, part1, mbuf, lbuf, x, gamma, out);
}

// Round 14
// 191.310 us; speedup vs baseline: 2.5945x; 1.0554x over previous
//
#include <hip/hip_runtime.h>
#include <hip/hip_bf16.h>
#include <math.h>

#define HW 4096
#define NC 512
#define NB 4

typedef float f32x4 __attribute__((ext_vector_type(4)));
typedef float f32x16 __attribute__((ext_vector_type(16)));
typedef short bf16x8 __attribute__((ext_vector_type(8)));
typedef unsigned int u32;
typedef u32 u32x4 __attribute__((ext_vector_type(4)));
typedef unsigned short ushort_t;

#define GLOAD_LDS(g, s) __builtin_amdgcn_global_load_lds((const __attribute__((address_space(1))) void*)(g), (__attribute__((address_space(3))) void*)(s), 16, 0, 0)

__device__ __forceinline__ unsigned short f2bf(float f){
  unsigned int u = __builtin_bit_cast(unsigned int, f);
  u += 0x7FFFu + ((u >> 16) & 1u);
  return (unsigned short)(u >> 16);
}
__device__ __forceinline__ float bf2f(unsigned short h){
  unsigned int u = ((unsigned int)h) << 16;
  return __builtin_bit_cast(float, u);
}

// ---------------- W -> bf16 hi (+lo for q/k rows 0..127) ----------------
__global__ __launch_bounds__(256) void wsplit_kernel(
    const float* __restrict__ Wq, const float* __restrict__ Wk,
    const float* __restrict__ Wv, ushort_t* __restrict__ wh, ushort_t* __restrict__ wl)
{
  long e = ((long)blockIdx.x * 256 + threadIdx.x) * 8;
  int r = (int)(e >> 9), c = (int)(e & 511);
  const float* src = (r < 64)  ? Wq + (long)r * 512 + c
                   : (r < 128) ? Wk + (long)(r - 64) * 512 + c
                               : Wv + (long)(r - 128) * 512 + c;
  f32x4 v0 = *reinterpret_cast<const f32x4*>(src);
  f32x4 v1 = *reinterpret_cast<const f32x4*>(src + 4);
  ushort_t h[8], l[8];
  #pragma unroll
  for (int j = 0; j < 4; j++){ h[j] = f2bf(v0[j]); l[j] = f2bf(v0[j] - bf2f(h[j])); }
  #pragma unroll
  for (int j = 0; j < 4; j++){ h[4+j] = f2bf(v1[j]); l[4+j] = f2bf(v1[j] - bf2f(h[4+j])); }
  *reinterpret_cast<bf16x8*>(wh + e) = *reinterpret_cast<bf16x8*>(h);
  if (r < 128) *reinterpret_cast<bf16x8*>(wl + e) = *reinterpret_cast<bf16x8*>(l);
}

// ---------------- x [b][c][px] fp32 -> xt hi [b][px][c] bf16 (lo dropped) ----------------
__global__ __launch_bounds__(256) void split_kernel(
    const float* __restrict__ x, ushort_t* __restrict__ xth)
{
  const int i0 = blockIdx.x * 64;
  const int c0 = blockIdx.y * 64;
  const int b  = blockIdx.z;
  const int tid = threadIdx.x;
  const int tx = tid & 63, ty = tid >> 6;
  __shared__ float ts[64][65];
  #pragma unroll
  for (int u = 0; u < 16; u++){
    int cl = ty * 16 + u;
    ts[cl][tx] = x[((long)b * NC + c0 + cl) * HW + i0 + tx];
  }
  __syncthreads();
  const int px = tid >> 2;
  const int cs = (tid & 3) * 16;
  ushort_t h[16];
  #pragma unroll
  for (int e = 0; e < 16; e++) h[e] = f2bf(ts[cs + e][px]);
  long base = ((long)b * HW + i0 + px) * 512 + c0 + cs;
  *reinterpret_cast<bf16x8*>(xth + base)     = *reinterpret_cast<bf16x8*>(h);
  *reinterpret_cast<bf16x8*>(xth + base + 8) = *reinterpret_cast<bf16x8*>(h + 8);
}

// ---------------- MFMA projection GEMM (xh only; q pre-scaled by log2 e) ----------------
// rg0: acc += xh·Wh + xh·Wl (2-term). rg>=1 (v): acc += Wh·xh (1-term).
// LDS 32K: dbuf[2] x 16KB xth tile [128px][64c] chunk-XOR-swizzled.
__global__ __launch_bounds__(256) void gemm_kernel(
    const ushort_t* __restrict__ xth,
    const ushort_t* __restrict__ wh, const ushort_t* __restrict__ wl,
    const float* __restrict__ bq, const float* __restrict__ bk, const float* __restrict__ bv,
    ushort_t* __restrict__ qhi, ushort_t* __restrict__ qlo,
    ushort_t* __restrict__ khi,
    ushort_t* __restrict__ vv)
{
  extern __shared__ char lds[];
  const int it = blockIdx.x;
  const int rg = blockIdx.y;
  const int b  = blockIdx.z;
  const int i0 = it * 128;
  const int tid = threadIdx.x;
  const int w = tid >> 6;
  const int lane = tid & 63;
  const int g = lane >> 4, n = lane & 15;
  const int wy = w >> 1, wx = w & 1;

  f32x4 acc[4][4];
  #pragma unroll
  for (int a = 0; a < 4; a++)
    #pragma unroll
    for (int m = 0; m < 4; m++) acc[a][m] = (f32x4){0.f, 0.f, 0.f, 0.f};

  const long xrow = (long)b * HW + i0;

  auto stage = [&](int bsel, int c0s){
    char* dbase = lds + bsel * 16384 + (w << 10);
    #pragma unroll
    for (int u = 0; u < 4; u++){
      int idx = (u << 8) | tid;
      int px = idx >> 3;
      int chs = (idx & 7) ^ (px & 7);
      long go = (xrow + px) * 512 + c0s + chs * 8;
      GLOAD_LDS(xth + go, dbase + (u << 12));
    }
  };

  stage(0, 0);
  asm volatile("s_waitcnt vmcnt(0)" ::: "memory");
  __syncthreads();

  int cur = 0;
  for (int t = 0; t < 8; t++){
    const int c0 = t << 6;
    bf16x8 wfh[4][2], wfl[4][2];
    #pragma unroll
    for (int a = 0; a < 4; a++){
      long R = (long)(rg * 128 + wx * 64 + a * 16 + n) * 512 + c0 + g * 8;
      wfh[a][0] = *reinterpret_cast<const bf16x8*>(wh + R);
      wfh[a][1] = *reinterpret_cast<const bf16x8*>(wh + R + 32);
    }
    if (rg == 0){
      #pragma unroll
      for (int a = 0; a < 4; a++){
        long R = (long)(wx * 64 + a * 16 + n) * 512 + c0 + g * 8;
        wfl[a][0] = *reinterpret_cast<const bf16x8*>(wl + R);
        wfl[a][1] = *reinterpret_cast<const bf16x8*>(wl + R + 32);
      }
    }
    if (t < 7) stage(cur ^ 1, (t + 1) << 6);
    bf16x8 xh[4][2];
    const char* buf = lds + cur * 16384;
    #pragma unroll
    for (int m = 0; m < 4; m++){
      int px = wy * 64 + m * 16 + n;
      const char* row = buf + px * 128;
      #pragma unroll
      for (int ks = 0; ks < 2; ks++){
        int off = (((ks << 2) | g) ^ (px & 7)) << 4;
        xh[m][ks] = *reinterpret_cast<const bf16x8*>(row + off);
      }
    }
    __builtin_amdgcn_s_setprio(1);
    if (rg == 0){
      #pragma unroll
      for (int a = 0; a < 4; a++)
        #pragma unroll
        for (int m = 0; m < 4; m++)
          #pragma unroll
          for (int ks = 0; ks < 2; ks++){
            acc[a][m] = __builtin_amdgcn_mfma_f32_16x16x32_bf16(xh[m][ks], wfh[a][ks], acc[a][m], 0, 0, 0);
            acc[a][m] = __builtin_amdgcn_mfma_f32_16x16x32_bf16(xh[m][ks], wfl[a][ks], acc[a][m], 0, 0, 0);
          }
    } else {
      #pragma unroll
      for (int a = 0; a < 4; a++)
        #pragma unroll
        for (int m = 0; m < 4; m++)
          #pragma unroll
          for (int ks = 0; ks < 2; ks++)
            acc[a][m] = __builtin_amdgcn_mfma_f32_16x16x32_bf16(wfh[a][ks], xh[m][ks], acc[a][m], 0, 0, 0);
    }
    __builtin_amdgcn_s_setprio(0);
    asm volatile("s_waitcnt vmcnt(0)" ::: "memory");
    __syncthreads();
    cur ^= 1;
  }

  if (rg == 0){
    ushort_t* hs = wx ? khi : qhi;
    const float* bias = wx ? bk : bq;
    const float qscale = wx ? 1.0f : 1.44269504088896f;  // q in log2 domain
    #pragma unroll
    for (int a = 0; a < 4; a++){
      float bb = bias[a * 16 + n];
      #pragma unroll
      for (int m = 0; m < 4; m++){
        #pragma unroll
        for (int r4 = 0; r4 < 4; r4++){
          int px = wy * 64 + m * 16 + g * 4 + r4;
          float v = (acc[a][m][r4] + bb) * qscale;
          ushort_t h = f2bf(v);
          long ad = (xrow + px) * 64 + a * 16 + n;
          hs[ad] = h;
          if (wx == 0) qlo[ad] = f2bf(v - bf2f(h));   // only q needs the lo surface
        }
      }
    }
  } else {
    #pragma unroll
    for (int a = 0; a < 4; a++){
      #pragma unroll
      for (int r4 = 0; r4 < 4; r4++){
        int C = (rg - 1) * 128 + wx * 64 + a * 16 + g * 4 + r4;
        float bb = bv[C];
        #pragma unroll
        for (int m = 0; m < 4; m++){
          int px = wy * 64 + m * 16 + n;
          vv[((long)b * NC + C) * HW + i0 + px] = f2bf(acc[a][m][r4] + bb);
        }
      }
    }
  }
}

// ---------------- flash attention: producer/consumer softmax dedup (round-10 proven) ----------------
__global__ __launch_bounds__(512, 1) void attn_kernel(
    const ushort_t* __restrict__ qhi, const ushort_t* __restrict__ qlo,
    const ushort_t* __restrict__ khi,
    const ushort_t* __restrict__ vv,
    ushort_t* __restrict__ p0, ushort_t* __restrict__ p1,
    float* __restrict__ mbuf, float* __restrict__ lbuf)
{
  extern __shared__ char smem[];
  const int VB = 8192, PB = 139264, FB = 155648;
  const int wgid = blockIdx.x;
  const int xcd = wgid & 7;
  const int jh = xcd >> 2;
  const int b  = xcd & 3;
  const int qt = wgid >> 3;
  const int tid = threadIdx.x;
  const int w = tid >> 6;
  const int lane = tid & 63;
  const int q32 = lane & 31;
  const int hh = lane >> 5;
  const bool producer = (w < 4);
  const int rg = producer ? w : (w - 4);
  const int ch = producer ? 0 : 1;
  const int i0w = qt * 128 + rg * 32;
  const int c0w = ch * 256;
  const int jbase = jh * 2048;
  const int ct256 = ((w & 3) << 6) | lane;

  bf16x8 aqh[4], aql[4];
  #pragma unroll
  for (int c = 0; c < 4; c++){
    long qb = ((long)b * HW + i0w + q32) * 64 + c * 16 + hh * 8;
    aqh[c] = *reinterpret_cast<const bf16x8*>(qhi + qb);
    aql[c] = *reinterpret_cast<const bf16x8*>(qlo + qb);
  }

  f32x16 acc[8];
  #pragma unroll
  for (int ct = 0; ct < 8; ct++)
    #pragma unroll
    for (int r = 0; r < 16; r++) acc[ct][r] = 0.f;
  float mrow = -1e30f, lrow = 0.f;

  {
    int kj = tid >> 3;
    int kd = (tid & 7) ^ (kj & 7);
    GLOAD_LDS(khi + ((long)b * HW + jbase + kj) * 64 + kd * 8, smem + (w << 10));
    #pragma unroll
    for (int r = 0; r < 8; r++){
      int ss = (r << 9) | tid;
      int c = ss >> 3;
      int jblk = (ss & 7) ^ (c & 7);
      GLOAD_LDS(vv + ((long)b * NC + c) * HW + jbase + jblk * 8,
                smem + VB + (r << 13) + (w << 10));
    }
  }
  asm volatile("s_waitcnt vmcnt(0)" ::: "memory");
  __syncthreads();

  int cur = 0;
  for (int t = 0; t < 32; t++){
    bf16x8 pa[4];
    if (producer){
      f32x16 sv[2];
      __builtin_amdgcn_s_setprio(1);
      #pragma unroll
      for (int jt = 0; jt < 2; jt++){
        int jrow = jt * 32 + q32;
        const char* krow = smem + jrow * 128;
        int r7 = jrow & 7;
        f32x16 s;
        #pragma unroll
        for (int r = 0; r < 16; r++) s[r] = 0.f;
        #pragma unroll
        for (int c = 0; c < 4; c++){
          int off = (((c << 1) | hh) ^ r7) << 4;
          bf16x8 kh = *(const bf16x8*)(krow + off);
          s = __builtin_amdgcn_mfma_f32_32x32x16_bf16(kh, aqh[c], s, 0, 0, 0);
          s = __builtin_amdgcn_mfma_f32_32x32x16_bf16(kh, aql[c], s, 0, 0, 0);
        }
        sv[jt] = s;
      }
      __builtin_amdgcn_s_setprio(0);
      f32x16 mx;
      #pragma unroll
      for (int r = 0; r < 16; r++) mx[r] = fmaxf(sv[0][r], sv[1][r]);
      float m8[8];
      #pragma unroll
      for (int r = 0; r < 8; r++) m8[r] = fmaxf(mx[r], mx[r + 8]);
      float m4a = fmaxf(m8[0], m8[4]), m4b = fmaxf(m8[1], m8[5]);
      float m4c = fmaxf(m8[2], m8[6]), m4d = fmaxf(m8[3], m8[7]);
      float tmx = fmaxf(fmaxf(m4a, m4b), fmaxf(m4c, m4d));
      tmx = fmaxf(tmx, __shfl_xor(tmx, 32));
      int upd = __any(tmx > mrow + 11.5f) ? 1 : 0;
      float sc = 1.f;
      if (upd){
        float mnew = fmaxf(mrow, tmx);
        sc = exp2f(mrow - mnew);
        lrow *= sc;
        #pragma unroll
        for (int ct = 0; ct < 8; ct++)
          #pragma unroll
          for (int r = 0; r < 16; r++) acc[ct][r] *= sc;
        mrow = mnew;
      }
      #pragma unroll
      for (int jt = 0; jt < 2; jt++)
        #pragma unroll
        for (int r = 0; r < 16; r++) sv[jt][r] = exp2f(sv[jt][r] - mrow);
      float rs = 0.f;
      #pragma unroll
      for (int r = 0; r < 16; r++) rs += sv[0][r] + sv[1][r];
      rs += __shfl_xor(rs, 32);
      lrow += rs;
      #pragma unroll
      for (int jt = 0; jt < 2; jt++){
        u32 pk[8];
        #pragma unroll
        for (int i = 0; i < 8; i++){
          float a = sv[jt][2 * i], bb = sv[jt][2 * i + 1];
          u32 d;
          asm("v_cvt_pk_bf16_f32 %0, %1, %2" : "=v"(d) : "v"(a), "v"(bb));
          pk[i] = d;
        }
        #pragma unroll
        for (int cc = 0; cc < 2; cc++){
          u32 a0 = pk[4 * cc + 0], b0 = pk[4 * cc + 2];
          u32 a1 = pk[4 * cc + 1], b1 = pk[4 * cc + 3];
          asm volatile("v_permlane32_swap_b32 %0, %1" : "+v"(a0), "+v"(b0));
          asm volatile("v_permlane32_swap_b32 %0, %1" : "+v"(a1), "+v"(b1));
          u32x4 wv;
          wv[0] = a0; wv[1] = a1; wv[2] = b0; wv[3] = b1;
          pa[jt * 2 + cc] = __builtin_bit_cast(bf16x8, wv);
        }
      }
      char* pb = smem + PB + rg * 4096 + lane * 64;
      #pragma unroll
      for (int i = 0; i < 4; i++)
        *reinterpret_cast<bf16x8*>(pb + ((i ^ (lane & 3)) << 4)) = pa[i];
      if (lane == 0) *(int*)(smem + FB + rg * 4) = upd;
      if (upd && hh == 0) *(float*)(smem + FB + 64 + rg * 128 + q32 * 4) = sc;
    } else {
      if (t < 31){
        char* dbase = smem + VB + ((cur ^ 1) << 16) + ((w & 3) << 10);
        int j0 = jbase + (t + 1) * 64;
        #pragma unroll
        for (int r = 0; r < 16; r++){
          int ss = (r << 8) | ct256;
          int c = ss >> 3;
          int jblk = (ss & 7) ^ (c & 7);
          GLOAD_LDS(vv + ((long)b * NC + c) * HW + j0 + jblk * 8, dbase + (r << 12));
        }
      }
    }
    __syncthreads();
    if (!producer){
      if (t < 31){
        int j0 = jbase + (t + 1) * 64;
        #pragma unroll
        for (int r = 0; r < 2; r++){
          int chunk = (r << 8) | ct256;
          int kj = chunk >> 3;
          int kd = (chunk & 7) ^ (kj & 7);
          GLOAD_LDS(khi + ((long)b * HW + j0 + kj) * 64 + kd * 8,
                    smem + (r << 12) + ((w & 3) << 10));
        }
      }
      const char* pb = smem + PB + rg * 4096 + lane * 64;
      #pragma unroll
      for (int i = 0; i < 4; i++)
        pa[i] = *reinterpret_cast<const bf16x8*>(pb + ((i ^ (lane & 3)) << 4));
      int updf = *(const int*)(smem + FB + rg * 4);
      if (updf){
        float sc = *(const float*)(smem + FB + 64 + rg * 128 + q32 * 4);
        #pragma unroll
        for (int ct = 0; ct < 8; ct++)
          #pragma unroll
          for (int r = 0; r < 16; r++) acc[ct][r] *= sc;
      }
    }
    {
      const char* vb = smem + VB + (cur << 16);
      __builtin_amdgcn_s_setprio(1);
      #pragma unroll
      for (int ct = 0; ct < 8; ct++){
        int row = c0w + ct * 32 + q32;
        const char* vrow = vb + row * 128;
        int r7 = row & 7;
        #pragma unroll
        for (int c = 0; c < 4; c++){
          int off = (((c << 1) | hh) ^ r7) << 4;
          bf16x8 vf = *(const bf16x8*)(vrow + off);
          acc[ct] = __builtin_amdgcn_mfma_f32_32x32x16_bf16(vf, pa[c], acc[ct], 0, 0, 0);
        }
      }
      __builtin_amdgcn_s_setprio(0);
    }
    asm volatile("s_waitcnt vmcnt(0)" ::: "memory");
    __syncthreads();
    cur ^= 1;
  }

  ushort_t* pd = jh ? p1 : p0;
  const int i = i0w + q32;
  #pragma unroll
  for (int ct = 0; ct < 8; ct++){
    #pragma unroll
    for (int r = 0; r < 16; r++){
      int c = c0w + ct * 32 + (r & 3) + 8 * (r >> 2) + 4 * hh;
      pd[((long)b * NC + c) * HW + i] = f2bf(acc[ct][r]);
    }
  }
  if (producer && lane < 32){
    int gi = b * HW + i0w + lane;
    mbuf[jh * (NB * HW) + gi] = mrow;
    lbuf[jh * (NB * HW) + gi] = lrow;
  }
}

// ---------------- combine halves + epilogue: out = gamma * O + x (vectorized) ----------------
__global__ __launch_bounds__(256) void comb_kernel(
    const ushort_t* __restrict__ p0, const ushort_t* __restrict__ p1,
    const float* __restrict__ mbuf, const float* __restrict__ lbuf,
    const float* __restrict__ x, const float* __restrict__ gamma,
    float* __restrict__ out)
{
  const int it = blockIdx.x;
  const int ct = blockIdx.y;
  const int b  = blockIdx.z;
  const int i0 = it * 128, c0 = ct * 64;
  const int tid = threadIdx.x;
  __shared__ float f0s[128], f1s[128];
  const float gm = gamma[0];
  if (tid < 128){
    int gi = b * HW + i0 + tid;
    float m0 = mbuf[gi], m1 = mbuf[NB * HW + gi];
    float l0 = lbuf[gi], l1 = lbuf[NB * HW + gi];
    float M = fmaxf(m0, m1);
    float w0 = exp2f(m0 - M), w1 = exp2f(m1 - M);
    float rden = 1.f / (w0 * l0 + w1 * l1);
    f0s[tid] = w0 * rden;
    f1s[tid] = w1 * rden;
  }
  __syncthreads();
  const int ig = (tid & 15) << 3;
  const int cb = tid >> 4;
  #pragma unroll
  for (int u = 0; u < 4; u++){
    int cl = c0 + cb + u * 16;
    long base = ((long)b * NC + cl) * HW + i0 + ig;
    bf16x8 a0 = *reinterpret_cast<const bf16x8*>(p0 + base);
    bf16x8 a1 = *reinterpret_cast<const bf16x8*>(p1 + base);
    f32x4 x0 = *reinterpret_cast<const f32x4*>(x + base);
    f32x4 x1 = *reinterpret_cast<const f32x4*>(x + base + 4);
    f32x4 o0, o1;
    #pragma unroll
    for (int e = 0; e < 4; e++){
      float v = f0s[ig + e] * bf2f((ushort_t)a0[e]) + f1s[ig + e] * bf2f((ushort_t)a1[e]);
      o0[e] = fmaf(gm, v, x0[e]);
    }
    #pragma unroll
    for (int e = 0; e < 4; e++){
      float v = f0s[ig + 4 + e] * bf2f((ushort_t)a0[4 + e]) + f1s[ig + 4 + e] * bf2f((ushort_t)a1[4 + e]);
      o1[e] = fmaf(gm, v, x1[e]);
    }
    *reinterpret_cast<f32x4*>(out + base) = o0;
    *reinterpret_cast<f32x4*>(out + base + 4) = o1;
  }
}

extern "C" void kernel_launch(void* const* d_in, const int* in_sizes, int n_in,
                              void* d_out, int out_size, void* d_ws, size_t ws_size,
                              hipStream_t stream)
{
  const float* x  = (const float*)d_in[0];
  const float* Wq = (const float*)d_in[1];
  const float* bq = (const float*)d_in[2];
  const float* Wk = (const float*)d_in[3];
  const float* bk = (const float*)d_in[4];
  const float* Wv = (const float*)d_in[5];
  const float* bv = (const float*)d_in[6];
  const float* gamma = (const float*)d_in[7];
  float* out = (float*)d_out;

  char* ws = (char*)d_ws;
  const size_t MB = 1024 * 1024;
  ushort_t* xth = (ushort_t*)(ws);                 // 16 MB, reused as partial0
  ushort_t* part1 = (ushort_t*)(ws + 16 * MB);     // 16 MB (was xtl)
  ushort_t* wh  = (ushort_t*)(ws + 32 * MB);       // 640 KB
  ushort_t* wl  = (ushort_t*)(ws + 32 * MB + 655360);  // 128 KB
  ushort_t* qhi = (ushort_t*)(ws + 33 * MB);       // 2 MB each
  ushort_t* qlo = (ushort_t*)(ws + 35 * MB);
  ushort_t* khi = (ushort_t*)(ws + 37 * MB);
  ushort_t* vv  = (ushort_t*)(ws + 41 * MB);       // 16 MB
  float*    mbuf = (float*)(ws + 57 * MB);         // 128 KB
  float*    lbuf = (float*)(ws + 57 * MB + 131072);// 128 KB
  ushort_t* part0 = xth;   // alias: xt dead after gemm

  wsplit_kernel<<<dim3(160), dim3(256), 0, stream>>>(Wq, Wk, Wv, wh, wl);
  split_kernel<<<dim3(64, 8, NB), dim3(256), 0, stream>>>(x, xth);

  const int GSMEM = 32768;
  hipFuncSetAttribute((const void*)gemm_kernel,
                      hipFuncAttributeMaxDynamicSharedMemorySize, GSMEM);
  gemm_kernel<<<dim3(32, 5, NB), dim3(256), GSMEM, stream>>>(
      xth, wh, wl, bq, bk, bv, qhi, qlo, khi, vv);

  const int ASMEM = 156672;  // 8K K + 128K V dbuf + 16K P + 1K flags
  hipFuncSetAttribute((const void*)attn_kernel,
                      hipFuncAttributeMaxDynamicSharedMemorySize, ASMEM);
  attn_kernel<<<dim3(256), dim3(512), ASMEM, stream>>>(
      qhi, qlo, khi, vv, part0, part1, mbuf, lbuf);

  comb_kernel<<<dim3(32, 8, NB), dim3(256), 0, stream>>>(
      part0, part1, mbuf, lbuf, x, gamma, out);
}

// Round 15
// 184.700 us; speedup vs baseline: 2.6873x; 1.0358x over previous
//
#include <hip/hip_runtime.h>
#include <hip/hip_bf16.h>
#include <math.h>

#define HW 4096
#define NC 512
#define NB 4

typedef float f32x4 __attribute__((ext_vector_type(4)));
typedef float f32x16 __attribute__((ext_vector_type(16)));
typedef short bf16x8 __attribute__((ext_vector_type(8)));
typedef unsigned int u32;
typedef u32 u32x4 __attribute__((ext_vector_type(4)));
typedef unsigned short ushort_t;

#define GLOAD_LDS(g, s) __builtin_amdgcn_global_load_lds((const __attribute__((address_space(1))) void*)(g), (__attribute__((address_space(3))) void*)(s), 16, 0, 0)

__device__ __forceinline__ unsigned short f2bf(float f){
  unsigned int u = __builtin_bit_cast(unsigned int, f);
  u += 0x7FFFu + ((u >> 16) & 1u);
  return (unsigned short)(u >> 16);
}
__device__ __forceinline__ float bf2f(unsigned short h){
  unsigned int u = ((unsigned int)h) << 16;
  return __builtin_bit_cast(float, u);
}

// ---------------- fused: x transpose->bf16 (y<8) + W split (y==8) ----------------
__global__ __launch_bounds__(256) void split_kernel(
    const float* __restrict__ x, ushort_t* __restrict__ xth,
    const float* __restrict__ Wq, const float* __restrict__ Wk,
    const float* __restrict__ Wv, ushort_t* __restrict__ wh, ushort_t* __restrict__ wl)
{
  const int tid = threadIdx.x;
  if (blockIdx.y == 8){
    // W-split slice: 160 useful blocks of (64 x-tiles x NB)
    int wb = blockIdx.z * 64 + blockIdx.x;
    if (wb >= 160) return;
    long e = ((long)wb * 256 + tid) * 8;
    int r = (int)(e >> 9), c = (int)(e & 511);
    const float* src = (r < 64)  ? Wq + (long)r * 512 + c
                     : (r < 128) ? Wk + (long)(r - 64) * 512 + c
                                 : Wv + (long)(r - 128) * 512 + c;
    f32x4 v0 = *reinterpret_cast<const f32x4*>(src);
    f32x4 v1 = *reinterpret_cast<const f32x4*>(src + 4);
    ushort_t h[8], l[8];
    #pragma unroll
    for (int j = 0; j < 4; j++){ h[j] = f2bf(v0[j]); l[j] = f2bf(v0[j] - bf2f(h[j])); }
    #pragma unroll
    for (int j = 0; j < 4; j++){ h[4+j] = f2bf(v1[j]); l[4+j] = f2bf(v1[j] - bf2f(h[4+j])); }
    *reinterpret_cast<bf16x8*>(wh + e) = *reinterpret_cast<bf16x8*>(h);
    if (r < 128) *reinterpret_cast<bf16x8*>(wl + e) = *reinterpret_cast<bf16x8*>(l);
    return;
  }
  const int i0 = blockIdx.x * 64;
  const int c0 = blockIdx.y * 64;
  const int b  = blockIdx.z;
  const int tx = tid & 63, ty = tid >> 6;
  __shared__ float ts[64][65];
  #pragma unroll
  for (int u = 0; u < 16; u++){
    int cl = ty * 16 + u;
    ts[cl][tx] = x[((long)b * NC + c0 + cl) * HW + i0 + tx];
  }
  __syncthreads();
  const int px = tid >> 2;
  const int cs = (tid & 3) * 16;
  ushort_t h[16];
  #pragma unroll
  for (int e = 0; e < 16; e++) h[e] = f2bf(ts[cs + e][px]);
  long base = ((long)b * HW + i0 + px) * 512 + c0 + cs;
  *reinterpret_cast<bf16x8*>(xth + base)     = *reinterpret_cast<bf16x8*>(h);
  *reinterpret_cast<bf16x8*>(xth + base + 8) = *reinterpret_cast<bf16x8*>(h + 8);
}

// ---------------- MFMA projection GEMM (xh only; q pre-scaled by log2 e) ----------------
__global__ __launch_bounds__(256) void gemm_kernel(
    const ushort_t* __restrict__ xth,
    const ushort_t* __restrict__ wh, const ushort_t* __restrict__ wl,
    const float* __restrict__ bq, const float* __restrict__ bk, const float* __restrict__ bv,
    ushort_t* __restrict__ qhi, ushort_t* __restrict__ qlo,
    ushort_t* __restrict__ khi,
    ushort_t* __restrict__ vv)
{
  extern __shared__ char lds[];
  const int it = blockIdx.x;
  const int rg = blockIdx.y;
  const int b  = blockIdx.z;
  const int i0 = it * 128;
  const int tid = threadIdx.x;
  const int w = tid >> 6;
  const int lane = tid & 63;
  const int g = lane >> 4, n = lane & 15;
  const int wy = w >> 1, wx = w & 1;

  f32x4 acc[4][4];
  #pragma unroll
  for (int a = 0; a < 4; a++)
    #pragma unroll
    for (int m = 0; m < 4; m++) acc[a][m] = (f32x4){0.f, 0.f, 0.f, 0.f};

  const long xrow = (long)b * HW + i0;

  auto stage = [&](int bsel, int c0s){
    char* dbase = lds + bsel * 16384 + (w << 10);
    #pragma unroll
    for (int u = 0; u < 4; u++){
      int idx = (u << 8) | tid;
      int px = idx >> 3;
      int chs = (idx & 7) ^ (px & 7);
      long go = (xrow + px) * 512 + c0s + chs * 8;
      GLOAD_LDS(xth + go, dbase + (u << 12));
    }
  };

  stage(0, 0);
  asm volatile("s_waitcnt vmcnt(0)" ::: "memory");
  __syncthreads();

  int cur = 0;
  for (int t = 0; t < 8; t++){
    const int c0 = t << 6;
    bf16x8 wfh[4][2], wfl[4][2];
    #pragma unroll
    for (int a = 0; a < 4; a++){
      long R = (long)(rg * 128 + wx * 64 + a * 16 + n) * 512 + c0 + g * 8;
      wfh[a][0] = *reinterpret_cast<const bf16x8*>(wh + R);
      wfh[a][1] = *reinterpret_cast<const bf16x8*>(wh + R + 32);
    }
    if (rg == 0){
      #pragma unroll
      for (int a = 0; a < 4; a++){
        long R = (long)(wx * 64 + a * 16 + n) * 512 + c0 + g * 8;
        wfl[a][0] = *reinterpret_cast<const bf16x8*>(wl + R);
        wfl[a][1] = *reinterpret_cast<const bf16x8*>(wl + R + 32);
      }
    }
    if (t < 7) stage(cur ^ 1, (t + 1) << 6);
    bf16x8 xh[4][2];
    const char* buf = lds + cur * 16384;
    #pragma unroll
    for (int m = 0; m < 4; m++){
      int px = wy * 64 + m * 16 + n;
      const char* row = buf + px * 128;
      #pragma unroll
      for (int ks = 0; ks < 2; ks++){
        int off = (((ks << 2) | g) ^ (px & 7)) << 4;
        xh[m][ks] = *reinterpret_cast<const bf16x8*>(row + off);
      }
    }
    __builtin_amdgcn_s_setprio(1);
    if (rg == 0){
      #pragma unroll
      for (int a = 0; a < 4; a++)
        #pragma unroll
        for (int m = 0; m < 4; m++)
          #pragma unroll
          for (int ks = 0; ks < 2; ks++){
            acc[a][m] = __builtin_amdgcn_mfma_f32_16x16x32_bf16(xh[m][ks], wfh[a][ks], acc[a][m], 0, 0, 0);
            acc[a][m] = __builtin_amdgcn_mfma_f32_16x16x32_bf16(xh[m][ks], wfl[a][ks], acc[a][m], 0, 0, 0);
          }
    } else {
      #pragma unroll
      for (int a = 0; a < 4; a++)
        #pragma unroll
        for (int m = 0; m < 4; m++)
          #pragma unroll
          for (int ks = 0; ks < 2; ks++)
            acc[a][m] = __builtin_amdgcn_mfma_f32_16x16x32_bf16(wfh[a][ks], xh[m][ks], acc[a][m], 0, 0, 0);
    }
    __builtin_amdgcn_s_setprio(0);
    asm volatile("s_waitcnt vmcnt(0)" ::: "memory");
    __syncthreads();
    cur ^= 1;
  }

  if (rg == 0){
    ushort_t* hs = wx ? khi : qhi;
    const float* bias = wx ? bk : bq;
    const float qscale = wx ? 1.0f : 1.44269504088896f;  // q in log2 domain
    #pragma unroll
    for (int a = 0; a < 4; a++){
      float bb = bias[a * 16 + n];
      #pragma unroll
      for (int m = 0; m < 4; m++){
        #pragma unroll
        for (int r4 = 0; r4 < 4; r4++){
          int px = wy * 64 + m * 16 + g * 4 + r4;
          float v = (acc[a][m][r4] + bb) * qscale;
          ushort_t h = f2bf(v);
          long ad = (xrow + px) * 64 + a * 16 + n;
          hs[ad] = h;
          if (wx == 0) qlo[ad] = f2bf(v - bf2f(h));
        }
      }
    }
  } else {
    #pragma unroll
    for (int a = 0; a < 4; a++){
      #pragma unroll
      for (int r4 = 0; r4 < 4; r4++){
        int C = (rg - 1) * 128 + wx * 64 + a * 16 + g * 4 + r4;
        float bb = bv[C];
        #pragma unroll
        for (int m = 0; m < 4; m++){
          int px = wy * 64 + m * 16 + n;
          vv[((long)b * NC + C) * HW + i0 + px] = f2bf(acc[a][m][r4] + bb);
        }
      }
    }
  }
}

// ---------------- flash attention: producer/consumer softmax dedup ----------------
// pa exchange uses plane layout (i*1024 + lane*16): 16B lane stride -> 2-way banks (free).
__global__ __launch_bounds__(512, 1) void attn_kernel(
    const ushort_t* __restrict__ qhi, const ushort_t* __restrict__ qlo,
    const ushort_t* __restrict__ khi,
    const ushort_t* __restrict__ vv,
    ushort_t* __restrict__ p0, ushort_t* __restrict__ p1,
    float* __restrict__ mbuf, float* __restrict__ lbuf)
{
  extern __shared__ char smem[];
  const int VB = 8192, PB = 139264, FB = 155648;
  const int wgid = blockIdx.x;
  const int xcd = wgid & 7;
  const int jh = xcd >> 2;
  const int b  = xcd & 3;
  const int qt = wgid >> 3;
  const int tid = threadIdx.x;
  const int w = tid >> 6;
  const int lane = tid & 63;
  const int q32 = lane & 31;
  const int hh = lane >> 5;
  const bool producer = (w < 4);
  const int rg = producer ? w : (w - 4);
  const int ch = producer ? 0 : 1;
  const int i0w = qt * 128 + rg * 32;
  const int c0w = ch * 256;
  const int jbase = jh * 2048;
  const int ct256 = ((w & 3) << 6) | lane;

  bf16x8 aqh[4], aql[4];
  #pragma unroll
  for (int c = 0; c < 4; c++){
    long qb = ((long)b * HW + i0w + q32) * 64 + c * 16 + hh * 8;
    aqh[c] = *reinterpret_cast<const bf16x8*>(qhi + qb);
    aql[c] = *reinterpret_cast<const bf16x8*>(qlo + qb);
  }

  f32x16 acc[8];
  #pragma unroll
  for (int ct = 0; ct < 8; ct++)
    #pragma unroll
    for (int r = 0; r < 16; r++) acc[ct][r] = 0.f;
  float mrow = -1e30f, lrow = 0.f;

  {
    int kj = tid >> 3;
    int kd = (tid & 7) ^ (kj & 7);
    GLOAD_LDS(khi + ((long)b * HW + jbase + kj) * 64 + kd * 8, smem + (w << 10));
    #pragma unroll
    for (int r = 0; r < 8; r++){
      int ss = (r << 9) | tid;
      int c = ss >> 3;
      int jblk = (ss & 7) ^ (c & 7);
      GLOAD_LDS(vv + ((long)b * NC + c) * HW + jbase + jblk * 8,
                smem + VB + (r << 13) + (w << 10));
    }
  }
  asm volatile("s_waitcnt vmcnt(0)" ::: "memory");
  __syncthreads();

  int cur = 0;
  for (int t = 0; t < 32; t++){
    bf16x8 pa[4];
    if (producer){
      f32x16 sv[2];
      __builtin_amdgcn_s_setprio(1);
      #pragma unroll
      for (int jt = 0; jt < 2; jt++){
        int jrow = jt * 32 + q32;
        const char* krow = smem + jrow * 128;
        int r7 = jrow & 7;
        f32x16 s;
        #pragma unroll
        for (int r = 0; r < 16; r++) s[r] = 0.f;
        #pragma unroll
        for (int c = 0; c < 4; c++){
          int off = (((c << 1) | hh) ^ r7) << 4;
          bf16x8 kh = *(const bf16x8*)(krow + off);
          s = __builtin_amdgcn_mfma_f32_32x32x16_bf16(kh, aqh[c], s, 0, 0, 0);
          s = __builtin_amdgcn_mfma_f32_32x32x16_bf16(kh, aql[c], s, 0, 0, 0);
        }
        sv[jt] = s;
      }
      __builtin_amdgcn_s_setprio(0);
      f32x16 mx;
      #pragma unroll
      for (int r = 0; r < 16; r++) mx[r] = fmaxf(sv[0][r], sv[1][r]);
      float m8[8];
      #pragma unroll
      for (int r = 0; r < 8; r++) m8[r] = fmaxf(mx[r], mx[r + 8]);
      float m4a = fmaxf(m8[0], m8[4]), m4b = fmaxf(m8[1], m8[5]);
      float m4c = fmaxf(m8[2], m8[6]), m4d = fmaxf(m8[3], m8[7]);
      float tmx = fmaxf(fmaxf(m4a, m4b), fmaxf(m4c, m4d));
      tmx = fmaxf(tmx, __shfl_xor(tmx, 32));
      int upd = __any(tmx > mrow + 11.5f) ? 1 : 0;
      float sc = 1.f;
      if (upd){
        float mnew = fmaxf(mrow, tmx);
        sc = exp2f(mrow - mnew);
        lrow *= sc;
        #pragma unroll
        for (int ct = 0; ct < 8; ct++)
          #pragma unroll
          for (int r = 0; r < 16; r++) acc[ct][r] *= sc;
        mrow = mnew;
      }
      #pragma unroll
      for (int jt = 0; jt < 2; jt++)
        #pragma unroll
        for (int r = 0; r < 16; r++) sv[jt][r] = exp2f(sv[jt][r] - mrow);
      float rs = 0.f;
      #pragma unroll
      for (int r = 0; r < 16; r++) rs += sv[0][r] + sv[1][r];
      rs += __shfl_xor(rs, 32);
      lrow += rs;
      #pragma unroll
      for (int jt = 0; jt < 2; jt++){
        u32 pk[8];
        #pragma unroll
        for (int i = 0; i < 8; i++){
          float a = sv[jt][2 * i], bb = sv[jt][2 * i + 1];
          u32 d;
          asm("v_cvt_pk_bf16_f32 %0, %1, %2" : "=v"(d) : "v"(a), "v"(bb));
          pk[i] = d;
        }
        #pragma unroll
        for (int cc = 0; cc < 2; cc++){
          u32 a0 = pk[4 * cc + 0], b0 = pk[4 * cc + 2];
          u32 a1 = pk[4 * cc + 1], b1 = pk[4 * cc + 3];
          asm volatile("v_permlane32_swap_b32 %0, %1" : "+v"(a0), "+v"(b0));
          asm volatile("v_permlane32_swap_b32 %0, %1" : "+v"(a1), "+v"(b1));
          u32x4 wv;
          wv[0] = a0; wv[1] = a1; wv[2] = b0; wv[3] = b1;
          pa[jt * 2 + cc] = __builtin_bit_cast(bf16x8, wv);
        }
      }
      // publish pa: plane layout, 16B lane stride (2-way banks, free)
      char* pb = smem + PB + rg * 4096 + (lane << 4);
      #pragma unroll
      for (int i = 0; i < 4; i++)
        *reinterpret_cast<bf16x8*>(pb + (i << 10)) = pa[i];
      if (lane == 0) *(int*)(smem + FB + rg * 4) = upd;
      if (upd && hh == 0) *(float*)(smem + FB + 64 + rg * 128 + q32 * 4) = sc;
    } else {
      if (t < 31){
        char* dbase = smem + VB + ((cur ^ 1) << 16) + ((w & 3) << 10);
        int j0 = jbase + (t + 1) * 64;
        #pragma unroll
        for (int r = 0; r < 16; r++){
          int ss = (r << 8) | ct256;
          int c = ss >> 3;
          int jblk = (ss & 7) ^ (c & 7);
          GLOAD_LDS(vv + ((long)b * NC + c) * HW + j0 + jblk * 8, dbase + (r << 12));
        }
      }
    }
    __syncthreads();
    if (!producer){
      if (t < 31){
        int j0 = jbase + (t + 1) * 64;
        #pragma unroll
        for (int r = 0; r < 2; r++){
          int chunk = (r << 8) | ct256;
          int kj = chunk >> 3;
          int kd = (chunk & 7) ^ (kj & 7);
          GLOAD_LDS(khi + ((long)b * HW + j0 + kj) * 64 + kd * 8,
                    smem + (r << 12) + ((w & 3) << 10));
        }
      }
      const char* pb = smem + PB + rg * 4096 + (lane << 4);
      #pragma unroll
      for (int i = 0; i < 4; i++)
        pa[i] = *reinterpret_cast<const bf16x8*>(pb + (i << 10));
      int updf = *(const int*)(smem + FB + rg * 4);
      if (updf){
        float sc = *(const float*)(smem + FB + 64 + rg * 128 + q32 * 4);
        #pragma unroll
        for (int ct = 0; ct < 8; ct++)
          #pragma unroll
          for (int r = 0; r < 16; r++) acc[ct][r] *= sc;
      }
    }
    {
      const char* vb = smem + VB + (cur << 16);
      __builtin_amdgcn_s_setprio(1);
      #pragma unroll
      for (int ct = 0; ct < 8; ct++){
        int row = c0w + ct * 32 + q32;
        const char* vrow = vb + row * 128;
        int r7 = row & 7;
        #pragma unroll
        for (int c = 0; c < 4; c++){
          int off = (((c << 1) | hh) ^ r7) << 4;
          bf16x8 vf = *(const bf16x8*)(vrow + off);
          acc[ct] = __builtin_amdgcn_mfma_f32_32x32x16_bf16(vf, pa[c], acc[ct], 0, 0, 0);
        }
      }
      __builtin_amdgcn_s_setprio(0);
    }
    asm volatile("s_waitcnt vmcnt(0)" ::: "memory");
    __syncthreads();
    cur ^= 1;
  }

  ushort_t* pd = jh ? p1 : p0;
  const int i = i0w + q32;
  #pragma unroll
  for (int ct = 0; ct < 8; ct++){
    #pragma unroll
    for (int r = 0; r < 16; r++){
      int c = c0w + ct * 32 + (r & 3) + 8 * (r >> 2) + 4 * hh;
      pd[((long)b * NC + c) * HW + i] = f2bf(acc[ct][r]);
    }
  }
  if (producer && lane < 32){
    int gi = b * HW + i0w + lane;
    mbuf[jh * (NB * HW) + gi] = mrow;
    lbuf[jh * (NB * HW) + gi] = lrow;
  }
}

// ---------------- combine halves + epilogue: out = gamma * O + x (vectorized) ----------------
__global__ __launch_bounds__(256) void comb_kernel(
    const ushort_t* __restrict__ p0, const ushort_t* __restrict__ p1,
    const float* __restrict__ mbuf, const float* __restrict__ lbuf,
    const float* __restrict__ x, const float* __restrict__ gamma,
    float* __restrict__ out)
{
  const int it = blockIdx.x;
  const int ct = blockIdx.y;
  const int b  = blockIdx.z;
  const int i0 = it * 128, c0 = ct * 64;
  const int tid = threadIdx.x;
  __shared__ float f0s[128], f1s[128];
  const float gm = gamma[0];
  if (tid < 128){
    int gi = b * HW + i0 + tid;
    float m0 = mbuf[gi], m1 = mbuf[NB * HW + gi];
    float l0 = lbuf[gi], l1 = lbuf[NB * HW + gi];
    float M = fmaxf(m0, m1);
    float w0 = exp2f(m0 - M), w1 = exp2f(m1 - M);
    float rden = 1.f / (w0 * l0 + w1 * l1);
    f0s[tid] = w0 * rden;
    f1s[tid] = w1 * rden;
  }
  __syncthreads();
  const int ig = (tid & 15) << 3;
  const int cb = tid >> 4;
  #pragma unroll
  for (int u = 0; u < 4; u++){
    int cl = c0 + cb + u * 16;
    long base = ((long)b * NC + cl) * HW + i0 + ig;
    bf16x8 a0 = *reinterpret_cast<const bf16x8*>(p0 + base);
    bf16x8 a1 = *reinterpret_cast<const bf16x8*>(p1 + base);
    f32x4 x0 = *reinterpret_cast<const f32x4*>(x + base);
    f32x4 x1 = *reinterpret_cast<const f32x4*>(x + base + 4);
    f32x4 o0, o1;
    #pragma unroll
    for (int e = 0; e < 4; e++){
      float v = f0s[ig + e] * bf2f((ushort_t)a0[e]) + f1s[ig + e] * bf2f((ushort_t)a1[e]);
      o0[e] = fmaf(gm, v, x0[e]);
    }
    #pragma unroll
    for (int e = 0; e < 4; e++){
      float v = f0s[ig + 4 + e] * bf2f((ushort_t)a0[4 + e]) + f1s[ig + 4 + e] * bf2f((ushort_t)a1[4 + e]);
      o1[e] = fmaf(gm, v, x1[e]);
    }
    *reinterpret_cast<f32x4*>(out + base) = o0;
    *reinterpret_cast<f32x4*>(out + base + 4) = o1;
  }
}

extern "C" void kernel_launch(void* const* d_in, const int* in_sizes, int n_in,
                              void* d_out, int out_size, void* d_ws, size_t ws_size,
                              hipStream_t stream)
{
  const float* x  = (const float*)d_in[0];
  const float* Wq = (const float*)d_in[1];
  const float* bq = (const float*)d_in[2];
  const float* Wk = (const float*)d_in[3];
  const float* bk = (const float*)d_in[4];
  const float* Wv = (const float*)d_in[5];
  const float* bv = (const float*)d_in[6];
  const float* gamma = (const float*)d_in[7];
  float* out = (float*)d_out;

  char* ws = (char*)d_ws;
  const size_t MB = 1024 * 1024;
  ushort_t* xth = (ushort_t*)(ws);                 // 16 MB, reused as partial0
  ushort_t* part1 = (ushort_t*)(ws + 16 * MB);     // 16 MB
  ushort_t* wh  = (ushort_t*)(ws + 32 * MB);       // 640 KB
  ushort_t* wl  = (ushort_t*)(ws + 32 * MB + 655360);  // 128 KB
  ushort_t* qhi = (ushort_t*)(ws + 33 * MB);       // 2 MB each
  ushort_t* qlo = (ushort_t*)(ws + 35 * MB);
  ushort_t* khi = (ushort_t*)(ws + 37 * MB);
  ushort_t* vv  = (ushort_t*)(ws + 41 * MB);       // 16 MB
  float*    mbuf = (float*)(ws + 57 * MB);         // 128 KB
  float*    lbuf = (float*)(ws + 57 * MB + 131072);// 128 KB
  ushort_t* part0 = xth;

  // fused x-split (y<8) + W-split (y==8)
  split_kernel<<<dim3(64, 9, NB), dim3(256), 0, stream>>>(
      x, xth, Wq, Wk, Wv, wh, wl);

  const int GSMEM = 32768;
  hipFuncSetAttribute((const void*)gemm_kernel,
                      hipFuncAttributeMaxDynamicSharedMemorySize, GSMEM);
  gemm_kernel<<<dim3(32, 5, NB), dim3(256), GSMEM, stream>>>(
      xth, wh, wl, bq, bk, bv, qhi, qlo, khi, vv);

  const int ASMEM = 156672;  // 8K K + 128K V dbuf + 16K P + 1K flags
  hipFuncSetAttribute((const void*)attn_kernel,
                      hipFuncAttributeMaxDynamicSharedMemorySize, ASMEM);
  attn_kernel<<<dim3(256), dim3(512), ASMEM, stream>>>(
      qhi, qlo, khi, vv, part0, part1, mbuf, lbuf);

  comb_kernel<<<dim3(32, 8, NB), dim3(256), 0, stream>>>(
      part0, part1, mbuf, lbuf, x, gamma, out);
}